// Round 3
// baseline (936.888 us; speedup 1.0000x reference)
//
#include <hip/hip_runtime.h>
#include <hip/hip_bf16.h>
#include <math.h>

// Problem constants
#define BB 4
#define SS 1024
#define DD 1024
#define EE 4
#define HID 2816
#define HC 1408         // HID chunk (2816 = 2*1408)
#define SIXD 6144
#define NSLOT 8704      // packed slot space (8192 + per-expert 128-padding)
#define NMB 68          // max m-blocks of 128 over packed slots

typedef __bf16 v8bf __attribute__((ext_vector_type(8)));
typedef float  v4f  __attribute__((ext_vector_type(4)));

__device__ __forceinline__ ushort f2bf(float f) {
    union { float f; unsigned u; } v; v.f = f;
    unsigned r = v.u + 0x7fff + ((v.u >> 16) & 1);   // RNE
    return (ushort)(r >> 16);
}
__device__ __forceinline__ float bf2f(ushort u) {
    union { unsigned u; float f; } v; v.u = ((unsigned)u) << 16;
    return v.f;
}
__device__ __forceinline__ void split_bf(float x, ushort& h, ushort& l) {
    h = f2bf(x);
    l = f2bf(x - bf2f(h));
}
__device__ __forceinline__ void gload16(const void* g, void* l) {
    __builtin_amdgcn_global_load_lds((const __attribute__((address_space(1))) void*)g,
                                     (__attribute__((address_space(3))) void*)l, 16, 0, 0);
}
// wait until at most N vector-memory ops outstanding; lgkm/exp untouched
template<int N> __device__ __forceinline__ void wait_vm() {
    __builtin_amdgcn_s_waitcnt((N & 15) | (0x7 << 4) | (0xF << 8) | ((N >> 4) << 14));
}

// Bijective XCD-aware blockIdx remap (m204 formula): each XCD gets a
// contiguous chunk of wid-space (bx fastest) -> B panel stays L2-resident
// across the chunk's m-sweep.
__device__ __forceinline__ void xcd_remap(int& bx, int& by) {
    const int gx = gridDim.x, gy = gridDim.y;
    const int nwg = gx * gy;
    const int wid = bx + gx * by;
    const int q = nwg >> 3, r = nwg & 7;
    const int xcd = wid & 7, loc = wid >> 3;
    const int pos = (xcd < r) ? (xcd * (q + 1) + loc)
                              : (r * (q + 1) + (xcd - r) * q + loc);
    bx = pos % gx; by = pos / gx;
}

// ---------------------------------------------------------------------------
// MFMA GEMM, 128(M)x64(N) tile, BK=32, 256 threads = 4 waves (each 32x64),
// C[M][N] = A[M][K] * B^T (B stored [N][K]), bf16 operands.
// SPLIT (attention path): 2-stage LDS, 2 barriers/K-step, 1-deep prefetch,
//   hi+lo pairs, 3 MFMA passes.
// LDS k-slot XOR swizzle (bank-conflict-free b128): writer pre-swizzles the
// GLOBAL source column, reader compensates.
// EPI: 0 fp32 store | 2 resgate x+gate*val | 5 split bf16 store
// ---------------------------------------------------------------------------
template<int EPI, bool SPLIT>
__global__ __launch_bounds__(256, 2) void mgemm(
    const ushort* __restrict__ Ah, const ushort* __restrict__ Al,
    const ushort* __restrict__ Bh, const ushort* __restrict__ Bl,
    void* __restrict__ Cv, ushort* __restrict__ C2,
    const float* __restrict__ f1, const float* __restrict__ f2,
    int K, int lda, int ldb, int ldc,
    long sA, long sB, long sC)
{
    constexpr int STG = SPLIT ? 12288 : 6144;        // ushorts per stage
    constexpr int BH  = SPLIT ? 8192 : 4096;         // B-hi offset in stage
    constexpr int L   = SPLIT ? 6 : 3;               // loads/thread/tile
    __shared__ __align__(16) ushort smem[2 * STG];

    const int tid  = threadIdx.x;
    const int wv   = tid >> 6, lane = tid & 63;

    int bx = blockIdx.x, by = blockIdx.y;
    xcd_remap(bx, by);
    const int n0 = bx * 64;
    const int m0 = by * 128;
    const long zA = (long)blockIdx.z * sA;
    const long zB = (long)blockIdx.z * sB;
    const long zC = (long)blockIdx.z * sC;

    const int lrow = tid >> 2;           // 0..63 (4 lanes per row)
    const int skq  = ((tid & 3) ^ ((tid >> 3) & 3)) * 8;   // swizzled src slot
    const int lm   = lane & 15;
    const int qs   = (((lane >> 4) ^ ((lm >> 1) & 3)) * 8); // swizzled read slot

    v4f acc[2][4];
    const v4f vzero = {0.f, 0.f, 0.f, 0.f};
    #pragma unroll
    for (int i = 0; i < 2; ++i)
        #pragma unroll
        for (int j = 0; j < 4; ++j) acc[i][j] = vzero;

    auto issue = [&](int kt, int st) {
        const long kk = (long)kt * 32 + skq;
        ushort* base = smem + st * STG;
        #pragma unroll
        for (int c = 0; c < 2; ++c) {
            const int row  = c * 64 + lrow;
            const int loff = (c * 64 + wv * 16) * 32;
            gload16(Ah + zA + (long)(m0 + row) * lda + kk, base + loff);
            if (SPLIT)
                gload16(Al + zA + (long)(m0 + row) * lda + kk, base + 4096 + loff);
        }
        {
            const int loff = wv * 16 * 32;
            gload16(Bh + zB + (long)(n0 + lrow) * ldb + kk, base + BH + loff);
            if (SPLIT)
                gload16(Bl + zB + (long)(n0 + lrow) * ldb + kk, base + BH + 2048 + loff);
        }
    };

    const int nk = K / 32;
    issue(0, 0);
    for (int kt = 0; kt < nk; ++kt) {
        const int stg = kt & 1;
        if (kt) __builtin_amdgcn_s_barrier();
        const bool hasNext = (kt + 1 < nk);
        if (hasNext) issue(kt + 1, stg ^ 1);
        if (hasNext) wait_vm<L>(); else wait_vm<0>();
        __builtin_amdgcn_s_barrier();
        const ushort* As = smem + stg * STG;
        v8bf a[2], b[4];
        #pragma unroll
        for (int i = 0; i < 2; ++i) a[i] = *(const v8bf*)(As + (wv*32 + 16*i + lm) * 32 + qs);
        #pragma unroll
        for (int j = 0; j < 4; ++j) b[j] = *(const v8bf*)(As + BH + (16*j + lm) * 32 + qs);
        #pragma unroll
        for (int i = 0; i < 2; ++i)
            #pragma unroll
            for (int j = 0; j < 4; ++j)
                acc[i][j] = __builtin_amdgcn_mfma_f32_16x16x32_bf16(a[i], b[j], acc[i][j], 0, 0, 0);
        if (SPLIT) {
            v8bf al[2], bl[4];
            #pragma unroll
            for (int i = 0; i < 2; ++i) al[i] = *(const v8bf*)(As + 4096 + (wv*32 + 16*i + lm) * 32 + qs);
            #pragma unroll
            for (int j = 0; j < 4; ++j) bl[j] = *(const v8bf*)(As + BH + 2048 + (16*j + lm) * 32 + qs);
            #pragma unroll
            for (int i = 0; i < 2; ++i)
                #pragma unroll
                for (int j = 0; j < 4; ++j) {
                    acc[i][j] = __builtin_amdgcn_mfma_f32_16x16x32_bf16(a[i],  bl[j], acc[i][j], 0, 0, 0);
                    acc[i][j] = __builtin_amdgcn_mfma_f32_16x16x32_bf16(al[i], b[j],  acc[i][j], 0, 0, 0);
                }
        }
    }

    const int r0 = (lane >> 4) * 4;
    #pragma unroll
    for (int i = 0; i < 2; ++i) {
        #pragma unroll
        for (int j = 0; j < 4; ++j) {
            const int colg = n0 + 16*j + lm;
            #pragma unroll
            for (int r = 0; r < 4; ++r) {
                const long rowg = (long)(m0 + wv*32 + 16*i + r0 + r);
                const long idx  = zC + rowg * ldc + colg;
                const float val = acc[i][j][r];
                if (EPI == 0) {
                    ((float*)Cv)[idx] = val;
                } else if (EPI == 2) {
                    ((float*)Cv)[idx] = f1[idx] + f2[(rowg >> 10) * SIXD + 2048 + colg] * val;
                } else if (EPI == 5) {
                    ushort h, l; split_bf(val, h, l);
                    ((ushort*)Cv)[idx] = h;
                    C2[idx] = l;
                }
            }
        }
    }
}

// ---------------------------------------------------------------------------
// MoE h1h3 fused GEMM: 128(M)x128(N) tile, 4 waves (2x2, each 64x64),
// dual B (w1,w3), gathered A rows, epilogue actb = bf16(sin(acc1)*acc2).
// K=1024, lda=1024, ldb=1024, ldc=HC.
// 3-stage LDS (72 KB), ONE barrier/K-step, 2-deep prefetch, counted vmcnt.
// 64x64 wave tile: 12 ds_read_b128 feed 32 MFMA (384 B/MFMA vs 640 before)
// -> LDS-read pipe no longer 4x oversubscribed vs matrix pipe.
// ---------------------------------------------------------------------------
__global__ __launch_bounds__(256, 2) void mgemm_h1h3(
    const ushort* __restrict__ Ah, const ushort* __restrict__ B1,
    const ushort* __restrict__ B2, ushort* __restrict__ Cb,
    const int* __restrict__ tokidx, const int* __restrict__ mbe,
    const int* __restrict__ mbm, long sB)
{
    constexpr int STG = 12288;  // A 4096 + B1 4096 + B2 4096 ushorts (24 KB)
    __shared__ __align__(16) ushort smem[3 * STG];

    const int tid  = threadIdx.x;
    const int wv   = tid >> 6, lane = tid & 63;
    const int wr   = wv >> 1, wc = wv & 1;

    int bx = blockIdx.x, by = blockIdx.y;
    xcd_remap(bx, by);
    const int n0 = bx * 128;
    const int eexp = mbe[by];
    if (eexp < 0) return;
    const int m0 = mbm[by];
    const long zB = (long)eexp * sB;

    const int lrow = tid >> 2;
    const int skq  = ((tid & 3) ^ ((tid >> 3) & 3)) * 8;    // swizzled src slot
    const int lm   = lane & 15;
    const int qs   = (((lane >> 4) ^ ((lm >> 1) & 3)) * 8); // swizzled read slot

    long arow[2];
    #pragma unroll
    for (int c = 0; c < 2; ++c) {
        const int t = tokidx[m0 + c * 64 + lrow];
        arow[c] = (t < 0) ? 0 : (long)t;
    }

    v4f acc[4][4], acc2[4][4];
    const v4f vzero = {0.f, 0.f, 0.f, 0.f};
    #pragma unroll
    for (int i = 0; i < 4; ++i)
        #pragma unroll
        for (int j = 0; j < 4; ++j) { acc[i][j] = vzero; acc2[i][j] = vzero; }

    auto issue = [&](int kt, int st) {
        const long kk = (long)kt * 32 + skq;
        ushort* base = smem + st * STG;
        #pragma unroll
        for (int c = 0; c < 2; ++c) {
            const int loff = (c * 64 + wv * 16) * 32;
            gload16(Ah + arow[c] * 1024 + kk, base + loff);
            gload16(B1 + zB + (long)(n0 + c * 64 + lrow) * 1024 + kk, base + 4096 + loff);
            gload16(B2 + zB + (long)(n0 + c * 64 + lrow) * 1024 + kk, base + 8192 + loff);
        }
    };

    issue(0, 0);
    issue(1, 1);
    for (int kt = 0; kt < 32; ++kt) {
        if (kt + 1 < 32) wait_vm<6>(); else wait_vm<0>();
        __builtin_amdgcn_s_barrier();
        if (kt + 2 < 32) issue(kt + 2, (kt + 2) % 3);
        const ushort* As = smem + (kt % 3) * STG;
        v8bf a[4], b1[4], b2[4];
        #pragma unroll
        for (int i = 0; i < 4; ++i) a[i] = *(const v8bf*)(As + (wr*64 + 16*i + lm) * 32 + qs);
        #pragma unroll
        for (int j = 0; j < 4; ++j) {
            b1[j] = *(const v8bf*)(As + 4096 + (wc*64 + 16*j + lm) * 32 + qs);
            b2[j] = *(const v8bf*)(As + 8192 + (wc*64 + 16*j + lm) * 32 + qs);
        }
        #pragma unroll
        for (int i = 0; i < 4; ++i)
            #pragma unroll
            for (int j = 0; j < 4; ++j) {
                acc[i][j]  = __builtin_amdgcn_mfma_f32_16x16x32_bf16(a[i], b1[j], acc[i][j],  0, 0, 0);
                acc2[i][j] = __builtin_amdgcn_mfma_f32_16x16x32_bf16(a[i], b2[j], acc2[i][j], 0, 0, 0);
            }
    }

    const int r0 = (lane >> 4) * 4;
    #pragma unroll
    for (int i = 0; i < 4; ++i)
        #pragma unroll
        for (int j = 0; j < 4; ++j) {
            const int colg = n0 + wc*64 + 16*j + lm;
            #pragma unroll
            for (int r = 0; r < 4; ++r) {
                const long rowg = (long)(m0 + wr*64 + 16*i + r0 + r);
                Cb[rowg * HC + colg] = f2bf(sinf(acc[i][j][r]) * acc2[i][j][r]);
            }
        }
}

// ---------------------------------------------------------------------------
// MoE w2 scatter GEMM: 128(M)x128(N) tile, 4 waves (2x2, each 64x64),
// A = actb slots [M][HC], B = w2T [N=1024][HC] per expert, K=HC=1408.
// 3-stage LDS (48 KB), ONE barrier/K-step, 2-deep prefetch.
// Epilogue: out[tok] += comb[tok,e] * val (atomic scatter).
// ---------------------------------------------------------------------------
__global__ __launch_bounds__(256, 2) void mgemm_w2(
    const ushort* __restrict__ Ah, const ushort* __restrict__ Bh,
    float* __restrict__ Cv, const float* __restrict__ comb,
    const int* __restrict__ tokidx, const int* __restrict__ mbe,
    const int* __restrict__ mbm, long sB)
{
    constexpr int STG = 8192;   // A 4096 + B 4096 ushorts (16 KB)
    __shared__ __align__(16) ushort smem[3 * STG];

    const int tid  = threadIdx.x;
    const int wv   = tid >> 6, lane = tid & 63;
    const int wr   = wv >> 1, wc = wv & 1;

    int bx = blockIdx.x, by = blockIdx.y;
    xcd_remap(bx, by);
    const int n0 = bx * 128;
    const int eexp = mbe[by];
    if (eexp < 0) return;
    const int m0 = mbm[by];
    const long zB = (long)eexp * sB;

    const int lrow = tid >> 2;
    const int skq  = ((tid & 3) ^ ((tid >> 3) & 3)) * 8;
    const int lm   = lane & 15;
    const int qs   = (((lane >> 4) ^ ((lm >> 1) & 3)) * 8);

    v4f acc[4][4];
    const v4f vzero = {0.f, 0.f, 0.f, 0.f};
    #pragma unroll
    for (int i = 0; i < 4; ++i)
        #pragma unroll
        for (int j = 0; j < 4; ++j) acc[i][j] = vzero;

    auto issue = [&](int kt, int st) {
        const long kk = (long)kt * 32 + skq;
        ushort* base = smem + st * STG;
        #pragma unroll
        for (int c = 0; c < 2; ++c) {
            const int loff = (c * 64 + wv * 16) * 32;
            gload16(Ah + (long)(m0 + c * 64 + lrow) * HC + kk, base + loff);
            gload16(Bh + zB + (long)(n0 + c * 64 + lrow) * HC + kk, base + 4096 + loff);
        }
    };

    const int nk = HC / 32;   // 44
    issue(0, 0);
    issue(1, 1);
    for (int kt = 0; kt < nk; ++kt) {
        if (kt + 1 < nk) wait_vm<4>(); else wait_vm<0>();
        __builtin_amdgcn_s_barrier();
        if (kt + 2 < nk) issue(kt + 2, (kt + 2) % 3);
        const ushort* As = smem + (kt % 3) * STG;
        v8bf a[4], b[4];
        #pragma unroll
        for (int i = 0; i < 4; ++i) a[i] = *(const v8bf*)(As + (wr*64 + 16*i + lm) * 32 + qs);
        #pragma unroll
        for (int j = 0; j < 4; ++j) b[j] = *(const v8bf*)(As + 4096 + (wc*64 + 16*j + lm) * 32 + qs);
        #pragma unroll
        for (int i = 0; i < 4; ++i)
            #pragma unroll
            for (int j = 0; j < 4; ++j)
                acc[i][j] = __builtin_amdgcn_mfma_f32_16x16x32_bf16(a[i], b[j], acc[i][j], 0, 0, 0);
    }

    const int r0 = (lane >> 4) * 4;
    #pragma unroll
    for (int i = 0; i < 4; ++i)
        #pragma unroll
        for (int r = 0; r < 4; ++r) {
            const int rowg = m0 + wr*64 + 16*i + r0 + r;
            const int t = tokidx[rowg];
            if (t >= 0) {
                const float cw = comb[t * 4 + eexp];
                #pragma unroll
                for (int j = 0; j < 4; ++j)
                    atomicAdd(Cv + (long)t * 1024 + n0 + wc*64 + 16*j + lm, cw * acc[i][j][r]);
            }
        }
}

// ---------------------------------------------------------------------------
// Transpose fp32 [K][N] -> bf16 [N][K], optional hi/lo split.
// ---------------------------------------------------------------------------
template<bool SP>
__global__ __launch_bounds__(256) void transp(
    const float* __restrict__ in, ushort* __restrict__ oh, ushort* __restrict__ ol,
    int ldin, int ldout, long sIn, long sOut)
{
    __shared__ float T[64][65];
    const int n0 = blockIdx.x * 64, k0 = blockIdx.y * 64;
    in += (long)blockIdx.z * sIn;
    oh += (long)blockIdx.z * sOut;
    if (SP) ol += (long)blockIdx.z * sOut;
    const int t = threadIdx.x;
    const int rr = t >> 4, c4 = (t & 15) * 4;
    #pragma unroll
    for (int p = 0; p < 4; ++p) {
        const int r = rr + p * 16;
        const float4 v = *(const float4*)(in + (long)(k0 + r) * ldin + n0 + c4);
        T[c4+0][r] = v.x; T[c4+1][r] = v.y; T[c4+2][r] = v.z; T[c4+3][r] = v.w;
    }
    __syncthreads();
    #pragma unroll
    for (int p = 0; p < 4; ++p) {
        const int idx = t + 256 * p;
        const int n = idx >> 4, c = (idx & 15) * 4;
        ushort4 wh, wl;
        float x0 = T[n][c], x1 = T[n][c+1], x2 = T[n][c+2], x3 = T[n][c+3];
        if (SP) {
            split_bf(x0, wh.x, wl.x); split_bf(x1, wh.y, wl.y);
            split_bf(x2, wh.z, wl.z); split_bf(x3, wh.w, wl.w);
        } else {
            wh.x = f2bf(x0); wh.y = f2bf(x1); wh.z = f2bf(x2); wh.w = f2bf(x3);
        }
        *(ushort4*)(oh + (long)(n0 + n) * ldout + k0 + c) = wh;
        if (SP) *(ushort4*)(ol + (long)(n0 + n) * ldout + k0 + c) = wl;
    }
}

// ---------------------------------------------------------------------------
__global__ __launch_bounds__(256) void ada_kernel(
    const float* __restrict__ adaln, const float* __restrict__ aw,
    const float* __restrict__ ab, float* __restrict__ ada)
{
    __shared__ float s[DD];
    const int b = blockIdx.y;
    const int tid = threadIdx.x;
    for (int i = tid; i < DD; i += 256) {
        const float v = adaln[(long)b * DD + i];
        s[i] = v / (1.f + expf(-v));
    }
    __syncthreads();
    const int n = blockIdx.x * 256 + tid;
    float acc = 0.f;
    for (int k = 0; k < DD; ++k) acc += s[k] * aw[(long)k * SIXD + n];
    ada[(long)b * SIXD + n] = acc + ab[n];
}

// LayerNorm over D=1024; OUT: 0 fp32, 1 split bf16 hi/lo, 2 bf16
template<int OUT, bool MOD>
__global__ __launch_bounds__(256) void ln_kernel(
    const float* __restrict__ x, const float* __restrict__ w, const float* __restrict__ bias,
    const float* __restrict__ ada, int scale_off, int shift_off,
    float* __restrict__ o32, ushort* __restrict__ oh, ushort* __restrict__ ol, float eps)
{
    const int row = blockIdx.x;
    const int b = row >> 10;
    const int tid = threadIdx.x;
    const float* xr = x + (long)row * DD;
    float v[4]; float s = 0.f, q = 0.f;
    #pragma unroll
    for (int i = 0; i < 4; ++i) { v[i] = xr[tid + 256*i]; s += v[i]; q += v[i]*v[i]; }
    __shared__ float rs_[256], rq_[256];
    rs_[tid] = s; rq_[tid] = q; __syncthreads();
    for (int off = 128; off > 0; off >>= 1) {
        if (tid < off) { rs_[tid] += rs_[tid+off]; rq_[tid] += rq_[tid+off]; }
        __syncthreads();
    }
    const float mu  = rs_[0] * (1.f/DD);
    const float var = rq_[0] * (1.f/DD) - mu*mu;
    const float rstd = rsqrtf(var + eps);
    const float* ar = ada + (long)b * SIXD;
    #pragma unroll
    for (int i = 0; i < 4; ++i) {
        const int d = tid + 256*i;
        float y = (v[i] - mu) * rstd * w[d] + bias[d];
        if (MOD) y = y * (1.f + ar[scale_off + d]) + ar[shift_off + d];
        const long idx = (long)row * DD + d;
        if (OUT == 0) o32[idx] = y;
        else if (OUT == 1) { ushort h, l; split_bf(y, h, l); oh[idx] = h; ol[idx] = l; }
        else oh[idx] = f2bf(y);
    }
}

// Row softmax over 1024 -> split bf16 hi/lo
__global__ __launch_bounds__(256) void softmax_split(
    const float* __restrict__ in, ushort* __restrict__ oh, ushort* __restrict__ ol)
{
    const long row = blockIdx.x;
    const float* p = in + row * 1024;
    const int tid = threadIdx.x;
    float v[4]; float mx = -INFINITY;
    #pragma unroll
    for (int i = 0; i < 4; ++i) { v[i] = p[tid + 256*i]; mx = fmaxf(mx, v[i]); }
    __shared__ float red[256];
    red[tid] = mx; __syncthreads();
    for (int off = 128; off > 0; off >>= 1) {
        if (tid < off) red[tid] = fmaxf(red[tid], red[tid+off]);
        __syncthreads();
    }
    const float rowmax = red[0];
    __syncthreads();
    float s = 0.f;
    #pragma unroll
    for (int i = 0; i < 4; ++i) { v[i] = expf(v[i] - rowmax); s += v[i]; }
    red[tid] = s; __syncthreads();
    for (int off = 128; off > 0; off >>= 1) {
        if (tid < off) red[tid] += red[tid+off];
        __syncthreads();
    }
    const float inv = 1.f / red[0];
    #pragma unroll
    for (int i = 0; i < 4; ++i) {
        ushort h, l; split_bf(v[i] * inv, h, l);
        oh[row*1024 + tid + 256*i] = h;
        ol[row*1024 + tid + 256*i] = l;
    }
}

// Fused: h2 = modulate(ln(x2)) fp32, logits = h2 @ rw + rb (exact router)
__global__ __launch_bounds__(256) void router_fused(
    const float* __restrict__ x2, const float* __restrict__ fw, const float* __restrict__ fb,
    const float* __restrict__ ada, const float* __restrict__ rw, const float* __restrict__ rb,
    float* __restrict__ logits)
{
    const int row = blockIdx.x;
    const int b = row >> 10;
    const int tid = threadIdx.x;
    const float* xr = x2 + (long)row * DD;
    float v[4]; float s = 0.f, q = 0.f;
    #pragma unroll
    for (int i = 0; i < 4; ++i) { v[i] = xr[tid + 256*i]; s += v[i]; q += v[i]*v[i]; }
    __shared__ float rs_[256], rq_[256];
    rs_[tid] = s; rq_[tid] = q; __syncthreads();
    for (int off = 128; off > 0; off >>= 1) {
        if (tid < off) { rs_[tid] += rs_[tid+off]; rq_[tid] += rq_[tid+off]; }
        __syncthreads();
    }
    const float mu  = rs_[0] * (1.f/DD);
    const float var = rq_[0] * (1.f/DD) - mu*mu;
    const float rstd = rsqrtf(var + 1e-5f);
    const float* ar = ada + (long)b * SIXD;
    float acc[4] = {0.f, 0.f, 0.f, 0.f};
    #pragma unroll
    for (int i = 0; i < 4; ++i) {
        const int d = tid + 256*i;
        float h = (v[i] - mu) * rstd * fw[d] + fb[d];
        h = h * (1.f + ar[4096 + d]) + ar[3072 + d];
        const float* r4 = rw + (long)d * 4;
        acc[0] += h*r4[0]; acc[1] += h*r4[1]; acc[2] += h*r4[2]; acc[3] += h*r4[3];
    }
    __syncthreads();
    __shared__ float red[256];
    for (int e = 0; e < EE; ++e) {
        red[tid] = acc[e]; __syncthreads();
        for (int off = 128; off > 0; off >>= 1) {
            if (tid < off) red[tid] += red[tid+off];
            __syncthreads();
        }
        if (tid == 0) logits[(long)row * EE + e] = red[0] + rb[e];
        __syncthreads();
    }
}

// ---------------------------------------------------------------------------
// Merged router post-processing (single block, 1024 threads):
// seq-dim L2 norms, softmax, top-2 combine, aux loss, packed compaction
// with 128-aligned per-expert offsets and m-block map.
// Slot order within an expert is nondeterministic (atomics) — harmless.
// ---------------------------------------------------------------------------
__global__ __launch_bounds__(1024) void router_all(
    const float* __restrict__ logits, float* __restrict__ comb,
    float* __restrict__ auxout, int* __restrict__ tokidx,
    int* __restrict__ mbe, int* __restrict__ mbm)
{
    __shared__ float pl[16384];
    __shared__ float red[1024];
    __shared__ float nrm_l[16];
    __shared__ int lc[4], loff[4], lpos[4];
    const int tid = threadIdx.x;
    const int wv = tid >> 6, ln = tid & 63;
    // 1. L2 norms over seq dim: wave wv handles (b,e) = (wv>>2, wv&3)
    {
        const int b = wv >> 2, e = wv & 3;
        float s = 0.f;
        for (int it = 0; it < 16; ++it) {
            const float v = logits[(((long)b << 10) + ln + (it << 6)) * 4 + e];
            s += v * v;
        }
        for (int off = 32; off > 0; off >>= 1) s += __shfl_down(s, off, 64);
        if (ln == 0) nrm_l[wv] = fmaxf(sqrtf(s), 1e-12f);
    }
    if (tid < 4) lc[tid] = 0;
    __syncthreads();
    // 2. softmax + top-2 per row (4 rows/thread) + counts
    float cloc[4][4];
    const int rbase = tid * 4;
    for (int rr = 0; rr < 4; ++rr) {
        const int row = rbase + rr;
        const int b = row >> 10;
        float l[4], p[4];
        #pragma unroll
        for (int e = 0; e < 4; ++e) l[e] = logits[(long)row*4 + e] / nrm_l[b*4 + e];
        const float mx = fmaxf(fmaxf(l[0], l[1]), fmaxf(l[2], l[3]));
        float s = 0.f;
        #pragma unroll
        for (int e = 0; e < 4; ++e) { p[e] = expf(l[e] - mx); s += p[e]; }
        const float inv = 1.f / s;
        #pragma unroll
        for (int e = 0; e < 4; ++e) { p[e] *= inv; pl[row*4 + e] = p[e]; }
        int i1 = 0;
        #pragma unroll
        for (int e = 1; e < 4; ++e) if (p[e] > p[i1]) i1 = e;
        int i2 = (i1 == 0) ? 1 : 0;
        #pragma unroll
        for (int e = 0; e < 4; ++e) if (e != i1 && p[e] > p[i2]) i2 = e;
        #pragma unroll
        for (int e = 0; e < 4; ++e) {
            const float c = (e == i1) ? p[i1] : ((e == i2) ? p[i2] : 0.f);
            cloc[rr][e] = c;
            comb[(long)row*4 + e] = c;
            if (c > 0.f) atomicAdd(&lc[e], 1);
        }
    }
    __syncthreads();
    // 3. aux = sum_{s,e} (1/4 - mean_b p)^2
    float acc = 0.f;
    for (int i = tid; i < 4096; i += 1024) {
        const int s = i >> 2, e = i & 3;
        const float avg = 0.25f * (pl[s*4+e] + pl[(1024+s)*4+e] +
                                   pl[(2048+s)*4+e] + pl[(3072+s)*4+e]);
        const float d = 0.25f - avg;
        acc += d * d;
    }
    red[tid] = acc; __syncthreads();
    for (int off = 512; off > 0; off >>= 1) {
        if (tid < off) red[tid] += red[tid+off];
        __syncthreads();
    }
    if (tid == 0) auxout[0] = red[0];
    // 4. 128-aligned offsets + m-block map
    if (tid == 0) {
        int off0 = 0, nb = 0;
        for (int e = 0; e < 4; ++e) {
            loff[e] = off0; lpos[e] = 0;
            const int mb = (lc[e] + 127) >> 7;
            for (int k = 0; k < mb; ++k) { mbe[nb] = e; mbm[nb] = off0 + k*128; ++nb; }
            off0 += mb << 7;
        }
        for (; nb < NMB; ++nb) { mbe[nb] = -1; mbm[nb] = 0; }
    }
    for (int i = tid; i < NSLOT; i += 1024) tokidx[i] = -1;
    __syncthreads();
    // 5. fill slots
    for (int rr = 0; rr < 4; ++rr) {
        const int row = rbase + rr;
        #pragma unroll
        for (int e = 0; e < 4; ++e)
            if (cloc[rr][e] > 0.f) {
                const int s = atomicAdd(&lpos[e], 1);
                tokidx[loff[e] + s] = row;
            }
    }
}

__global__ __launch_bounds__(256) void zero_kernel(float4* __restrict__ out)
{
    out[(long)blockIdx.x * 256 + threadIdx.x] = float4{0.f, 0.f, 0.f, 0.f};
}

// ---------------------------------------------------------------------------
extern "C" void kernel_launch(void* const* d_in, const int* in_sizes, int n_in,
                              void* d_out, int out_size, void* d_ws, size_t ws_size,
                              hipStream_t stream)
{
    (void)in_sizes; (void)n_in; (void)out_size; (void)ws_size;
    const float* x     = (const float*)d_in[0];
    const float* adaln = (const float*)d_in[2];
    const float* wq    = (const float*)d_in[3];
    const float* wk    = (const float*)d_in[4];
    const float* wv    = (const float*)d_in[5];
    const float* wo    = (const float*)d_in[6];
    const float* qn_w  = (const float*)d_in[7];
    const float* qn_b  = (const float*)d_in[8];
    const float* kn_w  = (const float*)d_in[9];
    const float* kn_b  = (const float*)d_in[10];
    const float* an_w  = (const float*)d_in[11];
    const float* an_b  = (const float*)d_in[12];
    const float* fn_w  = (const float*)d_in[13];
    const float* fn_b  = (const float*)d_in[14];
    const float* w1    = (const float*)d_in[15];
    const float* w2    = (const float*)d_in[16];
    const float* w3    = (const float*)d_in[17];
    const float* rw    = (const float*)d_in[18];
    const float* rb    = (const float*)d_in[19];
    const float* aw    = (const float*)d_in[20];
    const float* ab    = (const float*)d_in[21];
    float* out = (float*)d_out;

    const long NBAT = (long)SS * DD;          // 1048576
    const long NBUF = (long)BB * SS * DD;     // 4194304
#define MB(x) ((long)(x) * 1048576L)

    char* P = (char*)d_ws;
    float* ada    = (float*)P;                       // 24576 f
    float* logits = (float*)(P + 98304);             // 16384 f
    float* comb   = logits + 16384;                  // 16384 f
    int*   tokidx = (int*)(comb + 16384);            // NSLOT
    int*   mbe    = tokidx + NSLOT;                  // NMB
    int*   mbm    = mbe + NMB;                       // NMB

    char* A0 = P + MB(1);
    // [0,12): wqT/wkT/wvT split -> woT [0,4) -> w1Tc [0,11.5)
    ushort* wqT_h = (ushort*)(A0 + MB(0));  ushort* wqT_l = (ushort*)(A0 + MB(2));
    ushort* wkT_h = (ushort*)(A0 + MB(4));  ushort* wkT_l = (ushort*)(A0 + MB(6));
    ushort* wvT_h = (ushort*)(A0 + MB(8));  ushort* wvT_l = (ushort*)(A0 + MB(10));
    ushort* woT_h = (ushort*)(A0 + MB(0));  ushort* woT_l = (ushort*)(A0 + MB(2));
    ushort* w1Tc  = (ushort*)(A0 + MB(0));           // [E][1408][1024] bf16
    // [12,28): h split -> sc -> ao split -> actb [8704][1408] (24.5 MiB)
    ushort* h_h  = (ushort*)(A0 + MB(12));  ushort* h_l  = (ushort*)(A0 + MB(20));
    float*  sc   = (float*) (A0 + MB(12));
    ushort* ao_h = (ushort*)(A0 + MB(12));  ushort* ao_l = (ushort*)(A0 + MB(20));
    ushort* actb = (ushort*)(A0 + MB(12));
    // [28,44): q32/k32 (sequenced) -> at split
    float*  qk32 = (float*) (A0 + MB(28));
    ushort* at_h = (ushort*)(A0 + MB(28));  ushort* at_l = (ushort*)(A0 + MB(36));
    // [44,60): v split
    ushort* v_h  = (ushort*)(A0 + MB(44));  ushort* v_l  = (ushort*)(A0 + MB(52));
    // [60,76): qT split -> x2 -> w3Tc [60,71.5)
    ushort* qT_h = (ushort*)(A0 + MB(60));  ushort* qT_l = (ushort*)(A0 + MB(68));
    float*  x2   = (float*) (A0 + MB(60));
    ushort* w3Tc = (ushort*)(A0 + MB(60));
    // [76,92): kT split -> h2bf [76,84); w2Tc [84,95.5)
    ushort* kT_h = (ushort*)(A0 + MB(76));  ushort* kT_l = (ushort*)(A0 + MB(84));
    ushort* h2bf = (ushort*)(A0 + MB(76));
    ushort* w2Tc = (ushort*)(A0 + MB(84));           // [E][1024][1408] bf16

    const dim3 blk(256);

    // 1. adaLN vector
    ada_kernel<<<dim3(SIXD/256, BB), blk, 0, stream>>>(adaln, aw, ab, ada);

    // 2. attention weight transposes (split)
    transp<true><<<dim3(16,16,1), blk, 0, stream>>>(wq, wqT_h, wqT_l, 1024, 1024, 0, 0);
    transp<true><<<dim3(16,16,1), blk, 0, stream>>>(wk, wkT_h, wkT_l, 1024, 1024, 0, 0);
    transp<true><<<dim3(16,16,1), blk, 0, stream>>>(wv, wvT_h, wvT_l, 1024, 1024, 0, 0);

    // 3. h = modulate(ln(x)) -> split bf16
    ln_kernel<1,true><<<4096, blk, 0, stream>>>(x, an_w, an_b, ada, 1024, 0,
                                                nullptr, h_h, h_l, 1e-5f);

    // 4. q: project, LN, transpose-split
    mgemm<0,true><<<dim3(16,32,1), blk, 0, stream>>>(
        h_h, h_l, wqT_h, wqT_l, qk32, nullptr, nullptr, nullptr,
        1024, 1024, 1024, 1024, 0, 0, 0);
    ln_kernel<0,false><<<4096, blk, 0, stream>>>(qk32, qn_w, qn_b, ada, 0, 0, qk32, nullptr, nullptr, 1e-5f);
    transp<true><<<dim3(16,16,BB), blk, 0, stream>>>(qk32, qT_h, qT_l, 1024, 1024, NBAT, NBAT);

    // 5. k: project, LN, transpose-split
    mgemm<0,true><<<dim3(16,32,1), blk, 0, stream>>>(
        h_h, h_l, wkT_h, wkT_l, qk32, nullptr, nullptr, nullptr,
        1024, 1024, 1024, 1024, 0, 0, 0);
    ln_kernel<0,false><<<4096, blk, 0, stream>>>(qk32, kn_w, kn_b, ada, 0, 0, qk32, nullptr, nullptr, 1e-5f);
    transp<true><<<dim3(16,16,BB), blk, 0, stream>>>(qk32, kT_h, kT_l, 1024, 1024, NBAT, NBAT);

    // 6. v: project -> split store
    mgemm<5,true><<<dim3(16,32,1), blk, 0, stream>>>(
        h_h, h_l, wvT_h, wvT_l, v_h, v_l, nullptr, nullptr,
        1024, 1024, 1024, 1024, 0, 0, 0);

    // 7. wo transpose (into reclaimed wqT region)
    transp<true><<<dim3(16,16,1), blk, 0, stream>>>(wo, woT_h, woT_l, 1024, 1024, 0, 0);

    // 8. scores[b,d,e] = sum_s qT[b,d,s]*kT[b,e,s]
    mgemm<0,true><<<dim3(16,8,BB), blk, 0, stream>>>(
        qT_h, qT_l, kT_h, kT_l, sc, nullptr, nullptr, nullptr,
        1024, 1024, 1024, 1024, NBAT, NBAT, NBAT);

    // 9. softmax -> attn split
    softmax_split<<<4096, blk, 0, stream>>>(sc, at_h, at_l);

    // 10. ao[b,s,d] = sum_e v[b,s,e]*attn[b,d,e] -> split store
    mgemm<5,true><<<dim3(16,8,BB), blk, 0, stream>>>(
        v_h, v_l, at_h, at_l, ao_h, ao_l, nullptr, nullptr,
        1024, 1024, 1024, 1024, NBAT, NBAT, NBAT);

    // 11. x2 = x + gate_msa * (ao @ wo)
    mgemm<2,true><<<dim3(16,32,1), blk, 0, stream>>>(
        ao_h, ao_l, woT_h, woT_l, x2, nullptr, x, ada,
        1024, 1024, 1024, 1024, 0, 0, 0);

    // 12. h2 = modulate(ln(x2)) -> bf16 (MoE input)
    ln_kernel<2,true><<<4096, blk, 0, stream>>>(x2, fn_w, fn_b, ada, 4096, 3072,
                                                nullptr, h2bf, nullptr, 1e-5f);

    // 13. router (exact fp32) + merged post/aux/compaction, zero out
    router_fused<<<4096, blk, 0, stream>>>(x2, fn_w, fn_b, ada, rw, rb, logits);
    router_all<<<1, dim3(1024), 0, stream>>>(logits, comb, out + NBUF, tokidx, mbe, mbm);
    zero_kernel<<<dim3(4096), blk, 0, stream>>>((float4*)out);

    // 14. MoE: top-2 sparse, HID chunked by 1408
    for (int c = 0; c < HID/HC; ++c) {
        transp<false><<<dim3(22,16,4), blk, 0, stream>>>(
            w1 + (long)c*HC, w1Tc, nullptr, HID, 1024, (long)DD*HID, (long)HC*1024);
        transp<false><<<dim3(22,16,4), blk, 0, stream>>>(
            w3 + (long)c*HC, w3Tc, nullptr, HID, 1024, (long)DD*HID, (long)HC*1024);
        transp<false><<<dim3(16,22,4), blk, 0, stream>>>(
            w2 + (long)c*HC*DD, w2Tc, nullptr, DD, HC, (long)HID*DD, (long)DD*HC);
        // act[slot] = bf16( sin(h2@w1c) * (h2@w3c) )  (gathered rows, dual-B, 128x128)
        mgemm_h1h3<<<dim3(11, NMB), blk, 0, stream>>>(
            h2bf, w1Tc, w3Tc, actb, tokidx, mbe, mbm, (long)HC*1024);
        // out[token] += comb[token,e] * (act @ w2c)  (atomic scatter, 128x128)
        mgemm_w2<<<dim3(8, NMB), blk, 0, stream>>>(
            actb, w2Tc, out, comb, tokidx, mbe, mbm, (long)DD*HC);
    }
#undef MB
}

// Round 4
// 833.029 us; speedup vs baseline: 1.1247x; 1.1247x over previous
//
#include <hip/hip_runtime.h>
#include <hip/hip_bf16.h>
#include <math.h>

// Problem constants
#define BB 4
#define SS 1024
#define DD 1024
#define EE 4
#define HID 2816
#define HC 1408         // HID chunk (2816 = 2*1408)
#define SIXD 6144
#define NSLOT 8704      // packed slot space (8192 + per-expert 128-padding)
#define NMB 68          // max m-blocks of 128 over packed slots

typedef __bf16 v8bf __attribute__((ext_vector_type(8)));
typedef float  v4f  __attribute__((ext_vector_type(4)));

__device__ __forceinline__ ushort f2bf(float f) {
    union { float f; unsigned u; } v; v.f = f;
    unsigned r = v.u + 0x7fff + ((v.u >> 16) & 1);   // RNE
    return (ushort)(r >> 16);
}
__device__ __forceinline__ float bf2f(ushort u) {
    union { unsigned u; float f; } v; v.u = ((unsigned)u) << 16;
    return v.f;
}
__device__ __forceinline__ void split_bf(float x, ushort& h, ushort& l) {
    h = f2bf(x);
    l = f2bf(x - bf2f(h));
}
__device__ __forceinline__ void gload16(const void* g, void* l) {
    __builtin_amdgcn_global_load_lds((const __attribute__((address_space(1))) void*)g,
                                     (__attribute__((address_space(3))) void*)l, 16, 0, 0);
}
// wait until at most N vector-memory ops outstanding; lgkm/exp untouched
template<int N> __device__ __forceinline__ void wait_vm() {
    __builtin_amdgcn_s_waitcnt((N & 15) | (0x7 << 4) | (0xF << 8) | ((N >> 4) << 14));
}

// Bijective XCD-aware blockIdx remap (m204 formula): each XCD gets a
// contiguous chunk of wid-space (bx fastest).
__device__ __forceinline__ void xcd_remap(int& bx, int& by) {
    const int gx = gridDim.x, gy = gridDim.y;
    const int nwg = gx * gy;
    const int wid = bx + gx * by;
    const int q = nwg >> 3, r = nwg & 7;
    const int xcd = wid & 7, loc = wid >> 3;
    const int pos = (xcd < r) ? (xcd * (q + 1) + loc)
                              : (r * (q + 1) + (xcd - r) * q + loc);
    bx = pos % gx; by = pos / gx;
}

// Column-major XCD chunking: within each XCD's contiguous chunk, m (by) is
// fastest -> one n-column's B panel stays L2-resident across the m-sweep.
__device__ __forceinline__ void xcd_remap_cm(int& bx, int& by) {
    const int gx = gridDim.x, gy = gridDim.y;
    const int nwg = gx * gy;
    const int wid = bx + gx * by;
    const int q = nwg >> 3, r = nwg & 7;
    const int xcd = wid & 7, loc = wid >> 3;
    const int pos = (xcd < r) ? (xcd * (q + 1) + loc)
                              : (r * (q + 1) + (xcd - r) * q + loc);
    bx = pos / gy; by = pos % gy;
}

// MoE-grid L2 blocking: grid (gx even, gy) with gx*gy % 8 == 0.
// Global order: n-half major, m major, n-within-half fastest.
__device__ __forceinline__ void moe_remap(int& bx, int& by) {
    const int gx = gridDim.x, gy = gridDim.y;
    const int total = gx * gy;
    const int wid = bx + gx * by;
    if ((total & 7) || (gx & 1)) { xcd_remap(bx, by); return; }
    const int q = total >> 3;
    const int pos = (wid & 7) * q + (wid >> 3);
    const int NG = gx >> 1;
    const int gh = NG * gy;
    const int nh = pos / gh, r = pos % gh;
    by = r / NG;
    bx = nh * NG + (r % NG);
}

// ---------------------------------------------------------------------------
// MFMA GEMM, 128(M)x64(N) tile, BK=32, 256 threads = 4 waves (each 32x64),
// C[M][N] = A[M][K] * B^T (B stored [N][K]), bf16 operands.
// SPLIT (attention path): 2-stage LDS, 2 barriers/K-step, 1-deep prefetch,
//   hi+lo pairs, 3 MFMA passes.
// non-SPLIT (MoE w2 path): 3-stage LDS, ONE barrier/K-step, 2-deep prefetch,
//   counted vmcnt keeps next tile's loads in flight.
// LDS k-slot XOR swizzle (bank-conflict-free b128): writer pre-swizzles the
// GLOBAL source column, reader compensates.
// EPI: 0 fp32 store | 2 resgate x+gate*val | 5 split bf16 store |
//      7 atomic scatter out[tok] += comb*val
// ---------------------------------------------------------------------------
template<int EPI, bool SPLIT, bool MOE>
__global__ __launch_bounds__(256, 2) void mgemm(
    const ushort* __restrict__ Ah, const ushort* __restrict__ Al,
    const ushort* __restrict__ Bh, const ushort* __restrict__ Bl,
    void* __restrict__ Cv, ushort* __restrict__ C2,
    const float* __restrict__ f1, const float* __restrict__ f2,
    const int* __restrict__ tokidx, const int* __restrict__ mbe,
    const int* __restrict__ mbm,
    int K, int lda, int ldb, int ldc,
    long sA, long sB, long sC)
{
    constexpr int STG = SPLIT ? 12288 : 6144;        // ushorts per stage
    constexpr int BH  = SPLIT ? 8192 : 4096;         // B-hi offset in stage
    constexpr int L   = SPLIT ? 6 : 3;               // loads/thread/tile
    constexpr int NST = SPLIT ? 2 : 3;               // LDS stages
    __shared__ __align__(16) ushort smem[NST * STG];

    const int tid  = threadIdx.x;
    const int wv   = tid >> 6, lane = tid & 63;

    int bx = blockIdx.x, by = blockIdx.y;
    if (MOE) moe_remap(bx, by); else xcd_remap(bx, by);
    const int n0 = bx * 64;

    int eexp = 0, m0;
    if (MOE) {
        eexp = mbe[by];
        if (eexp < 0) return;
        m0 = mbm[by];
    } else {
        m0 = by * 128;
    }
    const long zA = MOE ? 0 : (long)blockIdx.z * sA;
    const long zB = MOE ? (long)eexp * sB : (long)blockIdx.z * sB;
    const long zC = MOE ? 0 : (long)blockIdx.z * sC;

    const int lrow = tid >> 2;           // 0..63 (4 lanes per row)
    const int skq  = ((tid & 3) ^ ((tid >> 3) & 3)) * 8;   // swizzled src slot
    const int lm   = lane & 15;
    const int qs   = (((lane >> 4) ^ ((lm >> 1) & 3)) * 8); // swizzled read slot

    v4f acc[2][4];
    const v4f vzero = {0.f, 0.f, 0.f, 0.f};
    #pragma unroll
    for (int i = 0; i < 2; ++i)
        #pragma unroll
        for (int j = 0; j < 4; ++j) acc[i][j] = vzero;

    auto issue = [&](int kt, int st) {
        const long kk = (long)kt * 32 + skq;
        ushort* base = smem + st * STG;
        #pragma unroll
        for (int c = 0; c < 2; ++c) {
            const int row  = c * 64 + lrow;
            const int loff = (c * 64 + wv * 16) * 32;
            gload16(Ah + zA + (long)(m0 + row) * lda + kk, base + loff);
            if (SPLIT)
                gload16(Al + zA + (long)(m0 + row) * lda + kk, base + 4096 + loff);
        }
        {
            const int loff = wv * 16 * 32;
            gload16(Bh + zB + (long)(n0 + lrow) * ldb + kk, base + BH + loff);
            if (SPLIT)
                gload16(Bl + zB + (long)(n0 + lrow) * ldb + kk, base + BH + 2048 + loff);
        }
    };

    const int nk = K / 32;
    issue(0, 0);
    if (!SPLIT && nk > 1) issue(1, 1);
    for (int kt = 0; kt < nk; ++kt) {
        const int stg = SPLIT ? (kt & 1) : (kt % 3);
        if (SPLIT) {
            if (kt) __builtin_amdgcn_s_barrier();
            const bool hasNext = (kt + 1 < nk);
            if (hasNext) issue(kt + 1, stg ^ 1);
            if (hasNext) wait_vm<L>(); else wait_vm<0>();
            __builtin_amdgcn_s_barrier();
        } else {
            if (kt + 1 < nk) wait_vm<L>(); else wait_vm<0>();
            __builtin_amdgcn_s_barrier();
            if (kt + 2 < nk) issue(kt + 2, (kt + 2) % 3);
        }
        const ushort* As = smem + stg * STG;
        v8bf a[2], b[4];
        #pragma unroll
        for (int i = 0; i < 2; ++i) a[i] = *(const v8bf*)(As + (wv*32 + 16*i + lm) * 32 + qs);
        #pragma unroll
        for (int j = 0; j < 4; ++j) b[j] = *(const v8bf*)(As + BH + (16*j + lm) * 32 + qs);
        #pragma unroll
        for (int i = 0; i < 2; ++i)
            #pragma unroll
            for (int j = 0; j < 4; ++j)
                acc[i][j] = __builtin_amdgcn_mfma_f32_16x16x32_bf16(a[i], b[j], acc[i][j], 0, 0, 0);
        if (SPLIT) {
            v8bf al[2], bl[4];
            #pragma unroll
            for (int i = 0; i < 2; ++i) al[i] = *(const v8bf*)(As + 4096 + (wv*32 + 16*i + lm) * 32 + qs);
            #pragma unroll
            for (int j = 0; j < 4; ++j) bl[j] = *(const v8bf*)(As + BH + 2048 + (16*j + lm) * 32 + qs);
            #pragma unroll
            for (int i = 0; i < 2; ++i)
                #pragma unroll
                for (int j = 0; j < 4; ++j) {
                    acc[i][j] = __builtin_amdgcn_mfma_f32_16x16x32_bf16(a[i],  bl[j], acc[i][j], 0, 0, 0);
                    acc[i][j] = __builtin_amdgcn_mfma_f32_16x16x32_bf16(al[i], b[j],  acc[i][j], 0, 0, 0);
                }
        }
    }

    const int r0 = (lane >> 4) * 4;
    if (EPI == 7) {
        #pragma unroll
        for (int i = 0; i < 2; ++i)
            #pragma unroll
            for (int r = 0; r < 4; ++r) {
                const int rowg = m0 + wv*32 + 16*i + r0 + r;
                const int t = tokidx[rowg];
                if (t >= 0) {
                    const float cw = f1[t * 4 + eexp];
                    #pragma unroll
                    for (int j = 0; j < 4; ++j)
                        atomicAdd((float*)Cv + (long)t * 1024 + n0 + 16*j + lm, cw * acc[i][j][r]);
                }
            }
    } else {
        #pragma unroll
        for (int i = 0; i < 2; ++i) {
            #pragma unroll
            for (int j = 0; j < 4; ++j) {
                const int colg = n0 + 16*j + lm;
                #pragma unroll
                for (int r = 0; r < 4; ++r) {
                    const long rowg = (long)(m0 + wv*32 + 16*i + r0 + r);
                    const long idx  = zC + rowg * ldc + colg;
                    const float val = acc[i][j][r];
                    if (EPI == 0) {
                        ((float*)Cv)[idx] = val;
                    } else if (EPI == 2) {
                        ((float*)Cv)[idx] = f1[idx] + f2[(rowg >> 10) * SIXD + 2048 + colg] * val;
                    } else if (EPI == 5) {
                        ushort h, l; split_bf(val, h, l);
                        ((ushort*)Cv)[idx] = h;
                        C2[idx] = l;
                    }
                }
            }
        }
    }
}

// ---------------------------------------------------------------------------
// MoE h1h3 fused GEMM v2: 128(M)x128(N) block, 512 threads = 8 waves (2x4),
// wave tile 64(M)x32(N), dual B (w1,w3). acc = 64 floats/wave (the proven
// clean-allocation size); 8 ds_read_b128 feed 16 MFMA (512 B/MFMA) and
// 128 MFMA per block-barrier. 3-stage LDS (72 KB), ONE barrier/K-step,
// 2-deep prefetch, wait_vm<3> (3 loads/thread/stage). #pragma unroll 1 +
// manual stage counters keep the loop compact (no x3 unroll -> no spill).
// ---------------------------------------------------------------------------
__global__ __launch_bounds__(512, 2) void mgemm_h1h3(
    const ushort* __restrict__ Ah, const ushort* __restrict__ B1,
    const ushort* __restrict__ B2, ushort* __restrict__ Cb,
    const int* __restrict__ tokidx, const int* __restrict__ mbe,
    const int* __restrict__ mbm, long sB)
{
    constexpr int STG = 12288;  // A 4096 + B1 4096 + B2 4096 ushorts (24 KB)
    __shared__ __align__(16) ushort smem[3 * STG];

    const int tid  = threadIdx.x;
    const int wv   = tid >> 6, lane = tid & 63;
    const int wr   = wv >> 2, wc = wv & 3;    // 2 x 4 wave grid

    int bx = blockIdx.x, by = blockIdx.y;
    xcd_remap_cm(bx, by);
    const int n0 = bx * 128;
    const int eexp = mbe[by];
    if (eexp < 0) return;
    const int m0 = mbm[by];
    const long zB = (long)eexp * sB;

    const int lrow = tid >> 2;                              // 0..127
    const int skq  = ((tid & 3) ^ ((tid >> 3) & 3)) * 8;    // swizzled src slot
    const int lm   = lane & 15;
    const int qs   = (((lane >> 4) ^ ((lm >> 1) & 3)) * 8); // swizzled read slot

    const int t = tokidx[m0 + lrow];
    const long arow = (t < 0) ? 0 : (long)t;

    v4f acc[4][2], acc2[4][2];
    const v4f vzero = {0.f, 0.f, 0.f, 0.f};
    #pragma unroll
    for (int i = 0; i < 4; ++i)
        #pragma unroll
        for (int j = 0; j < 2; ++j) { acc[i][j] = vzero; acc2[i][j] = vzero; }

    auto issue = [&](int kt, int st) {
        const long kk = (long)kt * 32 + skq;
        ushort* base = smem + st * STG;
        const int loff = wv * 16 * 32;                       // 16 rows per wave
        gload16(Ah + arow * 1024 + kk, base + loff);
        gload16(B1 + zB + (long)(n0 + lrow) * 1024 + kk, base + 4096 + loff);
        gload16(B2 + zB + (long)(n0 + lrow) * 1024 + kk, base + 8192 + loff);
    };

    issue(0, 0);
    issue(1, 1);
    int s_cur = 0, s_nxt = 2;
    #pragma unroll 1
    for (int kt = 0; kt < 32; ++kt) {
        if (kt + 1 < 32) wait_vm<3>(); else wait_vm<0>();
        __builtin_amdgcn_s_barrier();
        if (kt + 2 < 32) issue(kt + 2, s_nxt);
        const ushort* As = smem + s_cur * STG;
        v8bf a[4], b1[2], b2[2];
        #pragma unroll
        for (int i = 0; i < 4; ++i) a[i] = *(const v8bf*)(As + (wr*64 + 16*i + lm) * 32 + qs);
        #pragma unroll
        for (int j = 0; j < 2; ++j) {
            b1[j] = *(const v8bf*)(As + 4096 + (wc*32 + 16*j + lm) * 32 + qs);
            b2[j] = *(const v8bf*)(As + 8192 + (wc*32 + 16*j + lm) * 32 + qs);
        }
        #pragma unroll
        for (int i = 0; i < 4; ++i)
            #pragma unroll
            for (int j = 0; j < 2; ++j) {
                acc[i][j]  = __builtin_amdgcn_mfma_f32_16x16x32_bf16(a[i], b1[j], acc[i][j],  0, 0, 0);
                acc2[i][j] = __builtin_amdgcn_mfma_f32_16x16x32_bf16(a[i], b2[j], acc2[i][j], 0, 0, 0);
            }
        s_cur = (s_cur == 2) ? 0 : s_cur + 1;
        s_nxt = (s_nxt == 2) ? 0 : s_nxt + 1;
    }

    const int r0 = (lane >> 4) * 4;
    #pragma unroll
    for (int i = 0; i < 4; ++i)
        #pragma unroll
        for (int j = 0; j < 2; ++j) {
            const int colg = n0 + wc*32 + 16*j + lm;
            #pragma unroll
            for (int r = 0; r < 4; ++r) {
                const long rowg = (long)(m0 + wr*64 + 16*i + r0 + r);
                Cb[rowg * HC + colg] = f2bf(sinf(acc[i][j][r]) * acc2[i][j][r]);
            }
        }
}

// ---------------------------------------------------------------------------
// Transpose fp32 [K][N] -> bf16 [N][K], optional hi/lo split.
// ---------------------------------------------------------------------------
template<bool SP>
__global__ __launch_bounds__(256) void transp(
    const float* __restrict__ in, ushort* __restrict__ oh, ushort* __restrict__ ol,
    int ldin, int ldout, long sIn, long sOut)
{
    __shared__ float T[64][65];
    const int n0 = blockIdx.x * 64, k0 = blockIdx.y * 64;
    in += (long)blockIdx.z * sIn;
    oh += (long)blockIdx.z * sOut;
    if (SP) ol += (long)blockIdx.z * sOut;
    const int t = threadIdx.x;
    const int rr = t >> 4, c4 = (t & 15) * 4;
    #pragma unroll
    for (int p = 0; p < 4; ++p) {
        const int r = rr + p * 16;
        const float4 v = *(const float4*)(in + (long)(k0 + r) * ldin + n0 + c4);
        T[c4+0][r] = v.x; T[c4+1][r] = v.y; T[c4+2][r] = v.z; T[c4+3][r] = v.w;
    }
    __syncthreads();
    #pragma unroll
    for (int p = 0; p < 4; ++p) {
        const int idx = t + 256 * p;
        const int n = idx >> 4, c = (idx & 15) * 4;
        ushort4 wh, wl;
        float x0 = T[n][c], x1 = T[n][c+1], x2 = T[n][c+2], x3 = T[n][c+3];
        if (SP) {
            split_bf(x0, wh.x, wl.x); split_bf(x1, wh.y, wl.y);
            split_bf(x2, wh.z, wl.z); split_bf(x3, wh.w, wl.w);
        } else {
            wh.x = f2bf(x0); wh.y = f2bf(x1); wh.z = f2bf(x2); wh.w = f2bf(x3);
        }
        *(ushort4*)(oh + (long)(n0 + n) * ldout + k0 + c) = wh;
        if (SP) *(ushort4*)(ol + (long)(n0 + n) * ldout + k0 + c) = wl;
    }
}

// ---------------------------------------------------------------------------
__global__ __launch_bounds__(256) void ada_kernel(
    const float* __restrict__ adaln, const float* __restrict__ aw,
    const float* __restrict__ ab, float* __restrict__ ada)
{
    __shared__ float s[DD];
    const int b = blockIdx.y;
    const int tid = threadIdx.x;
    for (int i = tid; i < DD; i += 256) {
        const float v = adaln[(long)b * DD + i];
        s[i] = v / (1.f + expf(-v));
    }
    __syncthreads();
    const int n = blockIdx.x * 256 + tid;
    float acc = 0.f;
    for (int k = 0; k < DD; ++k) acc += s[k] * aw[(long)k * SIXD + n];
    ada[(long)b * SIXD + n] = acc + ab[n];
}

// LayerNorm over D=1024; OUT: 0 fp32, 1 split bf16 hi/lo, 2 bf16
template<int OUT, bool MOD>
__global__ __launch_bounds__(256) void ln_kernel(
    const float* __restrict__ x, const float* __restrict__ w, const float* __restrict__ bias,
    const float* __restrict__ ada, int scale_off, int shift_off,
    float* __restrict__ o32, ushort* __restrict__ oh, ushort* __restrict__ ol, float eps)
{
    const int row = blockIdx.x;
    const int b = row >> 10;
    const int tid = threadIdx.x;
    const float* xr = x + (long)row * DD;
    float v[4]; float s = 0.f, q = 0.f;
    #pragma unroll
    for (int i = 0; i < 4; ++i) { v[i] = xr[tid + 256*i]; s += v[i]; q += v[i]*v[i]; }
    __shared__ float rs_[256], rq_[256];
    rs_[tid] = s; rq_[tid] = q; __syncthreads();
    for (int off = 128; off > 0; off >>= 1) {
        if (tid < off) { rs_[tid] += rs_[tid+off]; rq_[tid] += rq_[tid+off]; }
        __syncthreads();
    }
    const float mu  = rs_[0] * (1.f/DD);
    const float var = rq_[0] * (1.f/DD) - mu*mu;
    const float rstd = rsqrtf(var + eps);
    const float* ar = ada + (long)b * SIXD;
    #pragma unroll
    for (int i = 0; i < 4; ++i) {
        const int d = tid + 256*i;
        float y = (v[i] - mu) * rstd * w[d] + bias[d];
        if (MOD) y = y * (1.f + ar[scale_off + d]) + ar[shift_off + d];
        const long idx = (long)row * DD + d;
        if (OUT == 0) o32[idx] = y;
        else if (OUT == 1) { ushort h, l; split_bf(y, h, l); oh[idx] = h; ol[idx] = l; }
        else oh[idx] = f2bf(y);
    }
}

// Row softmax over 1024 -> split bf16 hi/lo
__global__ __launch_bounds__(256) void softmax_split(
    const float* __restrict__ in, ushort* __restrict__ oh, ushort* __restrict__ ol)
{
    const long row = blockIdx.x;
    const float* p = in + row * 1024;
    const int tid = threadIdx.x;
    float v[4]; float mx = -INFINITY;
    #pragma unroll
    for (int i = 0; i < 4; ++i) { v[i] = p[tid + 256*i]; mx = fmaxf(mx, v[i]); }
    __shared__ float red[256];
    red[tid] = mx; __syncthreads();
    for (int off = 128; off > 0; off >>= 1) {
        if (tid < off) red[tid] = fmaxf(red[tid], red[tid+off]);
        __syncthreads();
    }
    const float rowmax = red[0];
    __syncthreads();
    float s = 0.f;
    #pragma unroll
    for (int i = 0; i < 4; ++i) { v[i] = expf(v[i] - rowmax); s += v[i]; }
    red[tid] = s; __syncthreads();
    for (int off = 128; off > 0; off >>= 1) {
        if (tid < off) red[tid] += red[tid+off];
        __syncthreads();
    }
    const float inv = 1.f / red[0];
    #pragma unroll
    for (int i = 0; i < 4; ++i) {
        ushort h, l; split_bf(v[i] * inv, h, l);
        oh[row*1024 + tid + 256*i] = h;
        ol[row*1024 + tid + 256*i] = l;
    }
}

// Fused: h2 = modulate(ln(x2)) fp32, logits = h2 @ rw + rb (exact router)
__global__ __launch_bounds__(256) void router_fused(
    const float* __restrict__ x2, const float* __restrict__ fw, const float* __restrict__ fb,
    const float* __restrict__ ada, const float* __restrict__ rw, const float* __restrict__ rb,
    float* __restrict__ logits)
{
    const int row = blockIdx.x;
    const int b = row >> 10;
    const int tid = threadIdx.x;
    const float* xr = x2 + (long)row * DD;
    float v[4]; float s = 0.f, q = 0.f;
    #pragma unroll
    for (int i = 0; i < 4; ++i) { v[i] = xr[tid + 256*i]; s += v[i]; q += v[i]*v[i]; }
    __shared__ float rs_[256], rq_[256];
    rs_[tid] = s; rq_[tid] = q; __syncthreads();
    for (int off = 128; off > 0; off >>= 1) {
        if (tid < off) { rs_[tid] += rs_[tid+off]; rq_[tid] += rq_[tid+off]; }
        __syncthreads();
    }
    const float mu  = rs_[0] * (1.f/DD);
    const float var = rq_[0] * (1.f/DD) - mu*mu;
    const float rstd = rsqrtf(var + 1e-5f);
    const float* ar = ada + (long)b * SIXD;
    float acc[4] = {0.f, 0.f, 0.f, 0.f};
    #pragma unroll
    for (int i = 0; i < 4; ++i) {
        const int d = tid + 256*i;
        float h = (v[i] - mu) * rstd * fw[d] + fb[d];
        h = h * (1.f + ar[4096 + d]) + ar[3072 + d];
        const float* r4 = rw + (long)d * 4;
        acc[0] += h*r4[0]; acc[1] += h*r4[1]; acc[2] += h*r4[2]; acc[3] += h*r4[3];
    }
    __syncthreads();
    __shared__ float red[256];
    for (int e = 0; e < EE; ++e) {
        red[tid] = acc[e]; __syncthreads();
        for (int off = 128; off > 0; off >>= 1) {
            if (tid < off) red[tid] += red[tid+off];
            __syncthreads();
        }
        if (tid == 0) logits[(long)row * EE + e] = red[0] + rb[e];
        __syncthreads();
    }
}

// ---------------------------------------------------------------------------
// Merged router post-processing (single block, 1024 threads):
// seq-dim L2 norms, softmax, top-2 combine, aux loss, packed compaction
// with 128-aligned per-expert offsets and m-block map.
// Slot order within an expert is nondeterministic (atomics) — harmless.
// ---------------------------------------------------------------------------
__global__ __launch_bounds__(1024) void router_all(
    const float* __restrict__ logits, float* __restrict__ comb,
    float* __restrict__ auxout, int* __restrict__ tokidx,
    int* __restrict__ mbe, int* __restrict__ mbm)
{
    __shared__ float pl[16384];
    __shared__ float red[1024];
    __shared__ float nrm_l[16];
    __shared__ int lc[4], loff[4], lpos[4];
    const int tid = threadIdx.x;
    const int wv = tid >> 6, ln = tid & 63;
    // 1. L2 norms over seq dim: wave wv handles (b,e) = (wv>>2, wv&3)
    {
        const int b = wv >> 2, e = wv & 3;
        float s = 0.f;
        for (int it = 0; it < 16; ++it) {
            const float v = logits[(((long)b << 10) + ln + (it << 6)) * 4 + e];
            s += v * v;
        }
        for (int off = 32; off > 0; off >>= 1) s += __shfl_down(s, off, 64);
        if (ln == 0) nrm_l[wv] = fmaxf(sqrtf(s), 1e-12f);
    }
    if (tid < 4) lc[tid] = 0;
    __syncthreads();
    // 2. softmax + top-2 per row (4 rows/thread) + counts
    float cloc[4][4];
    const int rbase = tid * 4;
    for (int rr = 0; rr < 4; ++rr) {
        const int row = rbase + rr;
        const int b = row >> 10;
        float l[4], p[4];
        #pragma unroll
        for (int e = 0; e < 4; ++e) l[e] = logits[(long)row*4 + e] / nrm_l[b*4 + e];
        const float mx = fmaxf(fmaxf(l[0], l[1]), fmaxf(l[2], l[3]));
        float s = 0.f;
        #pragma unroll
        for (int e = 0; e < 4; ++e) { p[e] = expf(l[e] - mx); s += p[e]; }
        const float inv = 1.f / s;
        #pragma unroll
        for (int e = 0; e < 4; ++e) { p[e] *= inv; pl[row*4 + e] = p[e]; }
        int i1 = 0;
        #pragma unroll
        for (int e = 1; e < 4; ++e) if (p[e] > p[i1]) i1 = e;
        int i2 = (i1 == 0) ? 1 : 0;
        #pragma unroll
        for (int e = 0; e < 4; ++e) if (e != i1 && p[e] > p[i2]) i2 = e;
        #pragma unroll
        for (int e = 0; e < 4; ++e) {
            const float c = (e == i1) ? p[i1] : ((e == i2) ? p[i2] : 0.f);
            cloc[rr][e] = c;
            comb[(long)row*4 + e] = c;
            if (c > 0.f) atomicAdd(&lc[e], 1);
        }
    }
    __syncthreads();
    // 3. aux = sum_{s,e} (1/4 - mean_b p)^2
    float acc = 0.f;
    for (int i = tid; i < 4096; i += 1024) {
        const int s = i >> 2, e = i & 3;
        const float avg = 0.25f * (pl[s*4+e] + pl[(1024+s)*4+e] +
                                   pl[(2048+s)*4+e] + pl[(3072+s)*4+e]);
        const float d = 0.25f - avg;
        acc += d * d;
    }
    red[tid] = acc; __syncthreads();
    for (int off = 512; off > 0; off >>= 1) {
        if (tid < off) red[tid] += red[tid+off];
        __syncthreads();
    }
    if (tid == 0) auxout[0] = red[0];
    // 4. 128-aligned offsets + m-block map
    if (tid == 0) {
        int off0 = 0, nb = 0;
        for (int e = 0; e < 4; ++e) {
            loff[e] = off0; lpos[e] = 0;
            const int mb = (lc[e] + 127) >> 7;
            for (int k = 0; k < mb; ++k) { mbe[nb] = e; mbm[nb] = off0 + k*128; ++nb; }
            off0 += mb << 7;
        }
        for (; nb < NMB; ++nb) { mbe[nb] = -1; mbm[nb] = 0; }
    }
    for (int i = tid; i < NSLOT; i += 1024) tokidx[i] = -1;
    __syncthreads();
    // 5. fill slots
    for (int rr = 0; rr < 4; ++rr) {
        const int row = rbase + rr;
        #pragma unroll
        for (int e = 0; e < 4; ++e)
            if (cloc[rr][e] > 0.f) {
                const int s = atomicAdd(&lpos[e], 1);
                tokidx[loff[e] + s] = row;
            }
    }
}

__global__ __launch_bounds__(256) void zero_kernel(float4* __restrict__ out)
{
    out[(long)blockIdx.x * 256 + threadIdx.x] = float4{0.f, 0.f, 0.f, 0.f};
}

// ---------------------------------------------------------------------------
extern "C" void kernel_launch(void* const* d_in, const int* in_sizes, int n_in,
                              void* d_out, int out_size, void* d_ws, size_t ws_size,
                              hipStream_t stream)
{
    (void)in_sizes; (void)n_in; (void)out_size; (void)ws_size;
    const float* x     = (const float*)d_in[0];
    const float* adaln = (const float*)d_in[2];
    const float* wq    = (const float*)d_in[3];
    const float* wk    = (const float*)d_in[4];
    const float* wv    = (const float*)d_in[5];
    const float* wo    = (const float*)d_in[6];
    const float* qn_w  = (const float*)d_in[7];
    const float* qn_b  = (const float*)d_in[8];
    const float* kn_w  = (const float*)d_in[9];
    const float* kn_b  = (const float*)d_in[10];
    const float* an_w  = (const float*)d_in[11];
    const float* an_b  = (const float*)d_in[12];
    const float* fn_w  = (const float*)d_in[13];
    const float* fn_b  = (const float*)d_in[14];
    const float* w1    = (const float*)d_in[15];
    const float* w2    = (const float*)d_in[16];
    const float* w3    = (const float*)d_in[17];
    const float* rw    = (const float*)d_in[18];
    const float* rb    = (const float*)d_in[19];
    const float* aw    = (const float*)d_in[20];
    const float* ab    = (const float*)d_in[21];
    float* out = (float*)d_out;

    const long NBAT = (long)SS * DD;          // 1048576
    const long NBUF = (long)BB * SS * DD;     // 4194304
#define MB(x) ((long)(x) * 1048576L)

    char* P = (char*)d_ws;
    float* ada    = (float*)P;                       // 24576 f
    float* logits = (float*)(P + 98304);             // 16384 f
    float* comb   = logits + 16384;                  // 16384 f
    int*   tokidx = (int*)(comb + 16384);            // NSLOT
    int*   mbe    = tokidx + NSLOT;                  // NMB
    int*   mbm    = mbe + NMB;                       // NMB

    char* A0 = P + MB(1);
    // [0,12): wqT/wkT/wvT split -> woT [0,4) -> w1Tc [0,11.5)
    ushort* wqT_h = (ushort*)(A0 + MB(0));  ushort* wqT_l = (ushort*)(A0 + MB(2));
    ushort* wkT_h = (ushort*)(A0 + MB(4));  ushort* wkT_l = (ushort*)(A0 + MB(6));
    ushort* wvT_h = (ushort*)(A0 + MB(8));  ushort* wvT_l = (ushort*)(A0 + MB(10));
    ushort* woT_h = (ushort*)(A0 + MB(0));  ushort* woT_l = (ushort*)(A0 + MB(2));
    ushort* w1Tc  = (ushort*)(A0 + MB(0));           // [E][1408][1024] bf16
    // [12,28): h split -> sc -> ao split -> actb [8704][1408] (24.5 MiB)
    ushort* h_h  = (ushort*)(A0 + MB(12));  ushort* h_l  = (ushort*)(A0 + MB(20));
    float*  sc   = (float*) (A0 + MB(12));
    ushort* ao_h = (ushort*)(A0 + MB(12));  ushort* ao_l = (ushort*)(A0 + MB(20));
    ushort* actb = (ushort*)(A0 + MB(12));
    // [28,44): q32/k32 (sequenced) -> at split
    float*  qk32 = (float*) (A0 + MB(28));
    ushort* at_h = (ushort*)(A0 + MB(28));  ushort* at_l = (ushort*)(A0 + MB(36));
    // [44,60): v split
    ushort* v_h  = (ushort*)(A0 + MB(44));  ushort* v_l  = (ushort*)(A0 + MB(52));
    // [60,76): qT split -> x2 -> w3Tc [60,71.5)
    ushort* qT_h = (ushort*)(A0 + MB(60));  ushort* qT_l = (ushort*)(A0 + MB(68));
    float*  x2   = (float*) (A0 + MB(60));
    ushort* w3Tc = (ushort*)(A0 + MB(60));
    // [76,92): kT split -> h2bf [76,84); w2Tc [84,95.5)
    ushort* kT_h = (ushort*)(A0 + MB(76));  ushort* kT_l = (ushort*)(A0 + MB(84));
    ushort* h2bf = (ushort*)(A0 + MB(76));
    ushort* w2Tc = (ushort*)(A0 + MB(84));           // [E][1024][1408] bf16

    const dim3 blk(256);

    // 1. adaLN vector
    ada_kernel<<<dim3(SIXD/256, BB), blk, 0, stream>>>(adaln, aw, ab, ada);

    // 2. attention weight transposes (split)
    transp<true><<<dim3(16,16,1), blk, 0, stream>>>(wq, wqT_h, wqT_l, 1024, 1024, 0, 0);
    transp<true><<<dim3(16,16,1), blk, 0, stream>>>(wk, wkT_h, wkT_l, 1024, 1024, 0, 0);
    transp<true><<<dim3(16,16,1), blk, 0, stream>>>(wv, wvT_h, wvT_l, 1024, 1024, 0, 0);

    // 3. h = modulate(ln(x)) -> split bf16
    ln_kernel<1,true><<<4096, blk, 0, stream>>>(x, an_w, an_b, ada, 1024, 0,
                                                nullptr, h_h, h_l, 1e-5f);

    // 4. q: project, LN, transpose-split
    mgemm<0,true,false><<<dim3(16,32,1), blk, 0, stream>>>(
        h_h, h_l, wqT_h, wqT_l, qk32, nullptr, nullptr, nullptr, nullptr, nullptr, nullptr,
        1024, 1024, 1024, 1024, 0, 0, 0);
    ln_kernel<0,false><<<4096, blk, 0, stream>>>(qk32, qn_w, qn_b, ada, 0, 0, qk32, nullptr, nullptr, 1e-5f);
    transp<true><<<dim3(16,16,BB), blk, 0, stream>>>(qk32, qT_h, qT_l, 1024, 1024, NBAT, NBAT);

    // 5. k: project, LN, transpose-split
    mgemm<0,true,false><<<dim3(16,32,1), blk, 0, stream>>>(
        h_h, h_l, wkT_h, wkT_l, qk32, nullptr, nullptr, nullptr, nullptr, nullptr, nullptr,
        1024, 1024, 1024, 1024, 0, 0, 0);
    ln_kernel<0,false><<<4096, blk, 0, stream>>>(qk32, kn_w, kn_b, ada, 0, 0, qk32, nullptr, nullptr, 1e-5f);
    transp<true><<<dim3(16,16,BB), blk, 0, stream>>>(qk32, kT_h, kT_l, 1024, 1024, NBAT, NBAT);

    // 6. v: project -> split store
    mgemm<5,true,false><<<dim3(16,32,1), blk, 0, stream>>>(
        h_h, h_l, wvT_h, wvT_l, v_h, v_l, nullptr, nullptr, nullptr, nullptr, nullptr,
        1024, 1024, 1024, 1024, 0, 0, 0);

    // 7. wo transpose (into reclaimed wqT region)
    transp<true><<<dim3(16,16,1), blk, 0, stream>>>(wo, woT_h, woT_l, 1024, 1024, 0, 0);

    // 8. scores[b,d,e] = sum_s qT[b,d,s]*kT[b,e,s]
    mgemm<0,true,false><<<dim3(16,8,BB), blk, 0, stream>>>(
        qT_h, qT_l, kT_h, kT_l, sc, nullptr, nullptr, nullptr, nullptr, nullptr, nullptr,
        1024, 1024, 1024, 1024, NBAT, NBAT, NBAT);

    // 9. softmax -> attn split
    softmax_split<<<4096, blk, 0, stream>>>(sc, at_h, at_l);

    // 10. ao[b,s,d] = sum_e v[b,s,e]*attn[b,d,e] -> split store
    mgemm<5,true,false><<<dim3(16,8,BB), blk, 0, stream>>>(
        v_h, v_l, at_h, at_l, ao_h, ao_l, nullptr, nullptr, nullptr, nullptr, nullptr,
        1024, 1024, 1024, 1024, NBAT, NBAT, NBAT);

    // 11. x2 = x + gate_msa * (ao @ wo)
    mgemm<2,true,false><<<dim3(16,32,1), blk, 0, stream>>>(
        ao_h, ao_l, woT_h, woT_l, x2, nullptr, x, ada, nullptr, nullptr, nullptr,
        1024, 1024, 1024, 1024, 0, 0, 0);

    // 12. h2 = modulate(ln(x2)) -> bf16 (MoE input)
    ln_kernel<2,true><<<4096, blk, 0, stream>>>(x2, fn_w, fn_b, ada, 4096, 3072,
                                                nullptr, h2bf, nullptr, 1e-5f);

    // 13. router (exact fp32) + merged post/aux/compaction, zero out
    router_fused<<<4096, blk, 0, stream>>>(x2, fn_w, fn_b, ada, rw, rb, logits);
    router_all<<<1, dim3(1024), 0, stream>>>(logits, comb, out + NBUF, tokidx, mbe, mbm);
    zero_kernel<<<dim3(4096), blk, 0, stream>>>((float4*)out);

    // 14. MoE: top-2 sparse, HID chunked by 1408
    for (int c = 0; c < HID/HC; ++c) {
        transp<false><<<dim3(22,16,4), blk, 0, stream>>>(
            w1 + (long)c*HC, w1Tc, nullptr, HID, 1024, (long)DD*HID, (long)HC*1024);
        transp<false><<<dim3(22,16,4), blk, 0, stream>>>(
            w3 + (long)c*HC, w3Tc, nullptr, HID, 1024, (long)DD*HID, (long)HC*1024);
        transp<false><<<dim3(16,22,4), blk, 0, stream>>>(
            w2 + (long)c*HC*DD, w2Tc, nullptr, DD, HC, (long)HID*DD, (long)DD*HC);
        // act[slot] = bf16( sin(h2@w1c) * (h2@w3c) )  (gathered rows, dual-B, 128x128 / 8 waves)
        mgemm_h1h3<<<dim3(11, NMB), dim3(512), 0, stream>>>(
            h2bf, w1Tc, w3Tc, actb, tokidx, mbe, mbm, (long)HC*1024);
        // out[token] += comb[token,e] * (act @ w2c)  (atomic scatter)
        mgemm<7,false,true><<<dim3(16, NMB), blk, 0, stream>>>(
            actb, nullptr, w2Tc, nullptr, out, nullptr, comb, nullptr, tokidx, mbe, mbm,
            HC, HC, HC, 1024, 0, (long)DD*HC, 0);
    }
#undef MB
}

// Round 5
// 794.852 us; speedup vs baseline: 1.1787x; 1.0480x over previous
//
#include <hip/hip_runtime.h>
#include <hip/hip_bf16.h>
#include <math.h>

// Problem constants
#define BB 4
#define SS 1024
#define DD 1024
#define EE 4
#define HID 2816
#define HC 1408         // HID chunk (2816 = 2*1408)
#define SIXD 6144
#define NSLOT 8704      // packed slot space (8192 + per-expert 128-padding)
#define NMB 68          // max m-blocks of 128 over packed slots

typedef __bf16 v8bf __attribute__((ext_vector_type(8)));
typedef float  v4f  __attribute__((ext_vector_type(4)));

__device__ __forceinline__ ushort f2bf(float f) {
    union { float f; unsigned u; } v; v.f = f;
    unsigned r = v.u + 0x7fff + ((v.u >> 16) & 1);   // RNE
    return (ushort)(r >> 16);
}
__device__ __forceinline__ float bf2f(ushort u) {
    union { unsigned u; float f; } v; v.u = ((unsigned)u) << 16;
    return v.f;
}
__device__ __forceinline__ void split_bf(float x, ushort& h, ushort& l) {
    h = f2bf(x);
    l = f2bf(x - bf2f(h));
}
__device__ __forceinline__ void gload16(const void* g, void* l) {
    __builtin_amdgcn_global_load_lds((const __attribute__((address_space(1))) void*)g,
                                     (__attribute__((address_space(3))) void*)l, 16, 0, 0);
}
// wait until at most N vector-memory ops outstanding; lgkm/exp untouched
template<int N> __device__ __forceinline__ void wait_vm() {
    __builtin_amdgcn_s_waitcnt((N & 15) | (0x7 << 4) | (0xF << 8) | ((N >> 4) << 14));
}

// Bijective XCD-aware blockIdx remap (m204 formula): each XCD gets a
// contiguous chunk of wid-space (bx fastest).
__device__ __forceinline__ void xcd_remap(int& bx, int& by) {
    const int gx = gridDim.x, gy = gridDim.y;
    const int nwg = gx * gy;
    const int wid = bx + gx * by;
    const int q = nwg >> 3, r = nwg & 7;
    const int xcd = wid & 7, loc = wid >> 3;
    const int pos = (xcd < r) ? (xcd * (q + 1) + loc)
                              : (r * (q + 1) + (xcd - r) * q + loc);
    bx = pos % gx; by = pos / gx;
}

// Column-major XCD chunking: within each XCD's contiguous chunk, m (by) is
// fastest -> one n-column's B panel stays L2-resident across the m-sweep.
__device__ __forceinline__ void xcd_remap_cm(int& bx, int& by) {
    const int gx = gridDim.x, gy = gridDim.y;
    const int nwg = gx * gy;
    const int wid = bx + gx * by;
    const int q = nwg >> 3, r = nwg & 7;
    const int xcd = wid & 7, loc = wid >> 3;
    const int pos = (xcd < r) ? (xcd * (q + 1) + loc)
                              : (r * (q + 1) + (xcd - r) * q + loc);
    bx = pos / gy; by = pos % gy;
}

// MoE-grid L2 blocking: grid (gx even, gy) with gx*gy % 8 == 0.
// Global order: n-half major, m major, n-within-half fastest.
__device__ __forceinline__ void moe_remap(int& bx, int& by) {
    const int gx = gridDim.x, gy = gridDim.y;
    const int total = gx * gy;
    const int wid = bx + gx * by;
    if ((total & 7) || (gx & 1)) { xcd_remap(bx, by); return; }
    const int q = total >> 3;
    const int pos = (wid & 7) * q + (wid >> 3);
    const int NG = gx >> 1;
    const int gh = NG * gy;
    const int nh = pos / gh, r = pos % gh;
    by = r / NG;
    bx = nh * NG + (r % NG);
}

// ---------------------------------------------------------------------------
// MFMA GEMM, 128(M)x64(N) tile, BK=32, 256 threads = 4 waves (each 32x64),
// C[M][N] = A[M][K] * B^T (B stored [N][K]), bf16 operands.
// 3-stage LDS, ONE barrier/K-step, 2-deep prefetch, counted vmcnt (next
// tile's loads stay in flight across the barrier).
// Safety: issue(kt+2) overwrites the stage last read at compute(kt-1); all
// waves passed barrier(kt) only after finishing compute(kt-1)'s ds_reads.
// LDS k-slot XOR swizzle (bank-conflict-free b128): writer pre-swizzles the
// GLOBAL source column, reader compensates.
// SPLIT: hi+lo pairs, 3 MFMA passes.
// EPI: 0 fp32 store | 2 resgate x+gate*val | 5 split bf16 store |
//      7 atomic scatter out[tok] += comb*val
// ---------------------------------------------------------------------------
template<int EPI, bool SPLIT, bool MOE>
__global__ __launch_bounds__(256, 2) void mgemm(
    const ushort* __restrict__ Ah, const ushort* __restrict__ Al,
    const ushort* __restrict__ Bh, const ushort* __restrict__ Bl,
    void* __restrict__ Cv, ushort* __restrict__ C2,
    const float* __restrict__ f1, const float* __restrict__ f2,
    const int* __restrict__ tokidx, const int* __restrict__ mbe,
    const int* __restrict__ mbm,
    int K, int lda, int ldb, int ldc,
    long sA, long sB, long sC)
{
    constexpr int STG = SPLIT ? 12288 : 6144;        // ushorts per stage
    constexpr int BH  = SPLIT ? 8192 : 4096;         // B-hi offset in stage
    constexpr int L   = SPLIT ? 6 : 3;               // loads/thread/tile
    __shared__ __align__(16) ushort smem[3 * STG];

    const int tid  = threadIdx.x;
    const int wv   = tid >> 6, lane = tid & 63;

    int bx = blockIdx.x, by = blockIdx.y;
    if (MOE) moe_remap(bx, by); else xcd_remap(bx, by);
    const int n0 = bx * 64;

    int eexp = 0, m0;
    if (MOE) {
        eexp = mbe[by];
        if (eexp < 0) return;
        m0 = mbm[by];
    } else {
        m0 = by * 128;
    }
    const long zA = MOE ? 0 : (long)blockIdx.z * sA;
    const long zB = MOE ? (long)eexp * sB : (long)blockIdx.z * sB;
    const long zC = MOE ? 0 : (long)blockIdx.z * sC;

    const int lrow = tid >> 2;           // 0..63 (4 lanes per row)
    const int skq  = ((tid & 3) ^ ((tid >> 3) & 3)) * 8;   // swizzled src slot
    const int lm   = lane & 15;
    const int qs   = (((lane >> 4) ^ ((lm >> 1) & 3)) * 8); // swizzled read slot

    v4f acc[2][4];
    const v4f vzero = {0.f, 0.f, 0.f, 0.f};
    #pragma unroll
    for (int i = 0; i < 2; ++i)
        #pragma unroll
        for (int j = 0; j < 4; ++j) acc[i][j] = vzero;

    auto issue = [&](int kt, int st) {
        const long kk = (long)kt * 32 + skq;
        ushort* base = smem + st * STG;
        #pragma unroll
        for (int c = 0; c < 2; ++c) {
            const int row  = c * 64 + lrow;
            const int loff = (c * 64 + wv * 16) * 32;
            gload16(Ah + zA + (long)(m0 + row) * lda + kk, base + loff);
            if (SPLIT)
                gload16(Al + zA + (long)(m0 + row) * lda + kk, base + 4096 + loff);
        }
        {
            const int loff = wv * 16 * 32;
            gload16(Bh + zB + (long)(n0 + lrow) * ldb + kk, base + BH + loff);
            if (SPLIT)
                gload16(Bl + zB + (long)(n0 + lrow) * ldb + kk, base + BH + 2048 + loff);
        }
    };

    const int nk = K / 32;
    issue(0, 0);
    if (nk > 1) issue(1, 1);
    for (int kt = 0; kt < nk; ++kt) {
        if (kt + 1 < nk) wait_vm<L>(); else wait_vm<0>();
        __builtin_amdgcn_s_barrier();
        if (kt + 2 < nk) issue(kt + 2, (kt + 2) % 3);
        const ushort* As = smem + (kt % 3) * STG;
        v8bf a[2], b[4];
        #pragma unroll
        for (int i = 0; i < 2; ++i) a[i] = *(const v8bf*)(As + (wv*32 + 16*i + lm) * 32 + qs);
        #pragma unroll
        for (int j = 0; j < 4; ++j) b[j] = *(const v8bf*)(As + BH + (16*j + lm) * 32 + qs);
        #pragma unroll
        for (int i = 0; i < 2; ++i)
            #pragma unroll
            for (int j = 0; j < 4; ++j)
                acc[i][j] = __builtin_amdgcn_mfma_f32_16x16x32_bf16(a[i], b[j], acc[i][j], 0, 0, 0);
        if (SPLIT) {
            v8bf al[2], bl[4];
            #pragma unroll
            for (int i = 0; i < 2; ++i) al[i] = *(const v8bf*)(As + 4096 + (wv*32 + 16*i + lm) * 32 + qs);
            #pragma unroll
            for (int j = 0; j < 4; ++j) bl[j] = *(const v8bf*)(As + BH + 2048 + (16*j + lm) * 32 + qs);
            #pragma unroll
            for (int i = 0; i < 2; ++i)
                #pragma unroll
                for (int j = 0; j < 4; ++j) {
                    acc[i][j] = __builtin_amdgcn_mfma_f32_16x16x32_bf16(a[i],  bl[j], acc[i][j], 0, 0, 0);
                    acc[i][j] = __builtin_amdgcn_mfma_f32_16x16x32_bf16(al[i], b[j],  acc[i][j], 0, 0, 0);
                }
        }
    }

    const int r0 = (lane >> 4) * 4;
    if (EPI == 7) {
        #pragma unroll
        for (int i = 0; i < 2; ++i)
            #pragma unroll
            for (int r = 0; r < 4; ++r) {
                const int rowg = m0 + wv*32 + 16*i + r0 + r;
                const int t = tokidx[rowg];
                if (t >= 0) {
                    const float cw = f1[t * 4 + eexp];
                    #pragma unroll
                    for (int j = 0; j < 4; ++j)
                        atomicAdd((float*)Cv + (long)t * 1024 + n0 + 16*j + lm, cw * acc[i][j][r]);
                }
            }
    } else {
        #pragma unroll
        for (int i = 0; i < 2; ++i) {
            #pragma unroll
            for (int j = 0; j < 4; ++j) {
                const int colg = n0 + 16*j + lm;
                #pragma unroll
                for (int r = 0; r < 4; ++r) {
                    const long rowg = (long)(m0 + wv*32 + 16*i + r0 + r);
                    const long idx  = zC + rowg * ldc + colg;
                    const float val = acc[i][j][r];
                    if (EPI == 0) {
                        ((float*)Cv)[idx] = val;
                    } else if (EPI == 2) {
                        ((float*)Cv)[idx] = f1[idx] + f2[(rowg >> 10) * SIXD + 2048 + colg] * val;
                    } else if (EPI == 5) {
                        ushort h, l; split_bf(val, h, l);
                        ((ushort*)Cv)[idx] = h;
                        C2[idx] = l;
                    }
                }
            }
        }
    }
}

// ---------------------------------------------------------------------------
// Fused QKV GEMM: one pass over A (h split) computes q, k, v.
// 128(M)x64(N) tile, 4 waves (32x64), SPLIT precision (3 MFMA passes each).
// Stage = A hi/lo (16 KB) + 3 x B hi/lo (8 KB) = 40 KB; 2 stages = 80 KB,
// 2 blocks/CU. A staged ONCE feeds 72 MFMA/wave/K-step (vs 3x24 with 3x A
// traffic in separate kernels); barriers amortize 3x.
// Epilogues: q,k -> fp32 stores; v -> split bf16 store.
// ---------------------------------------------------------------------------
__global__ __launch_bounds__(256, 2) void mgemm_qkv(
    const ushort* __restrict__ Ah, const ushort* __restrict__ Al,
    const ushort* __restrict__ Bqh, const ushort* __restrict__ Bql,
    const ushort* __restrict__ Bkh, const ushort* __restrict__ Bkl,
    const ushort* __restrict__ Bvh, const ushort* __restrict__ Bvl,
    float* __restrict__ Cq, float* __restrict__ Ck,
    ushort* __restrict__ Cvh, ushort* __restrict__ Cvl)
{
    constexpr int STG = 20480;   // A 8192 + 3 * 4096 (Bh 2048 + Bl 2048)
    __shared__ __align__(16) ushort smem[2 * STG];

    const int tid  = threadIdx.x;
    const int wv   = tid >> 6, lane = tid & 63;

    int bx = blockIdx.x, by = blockIdx.y;
    xcd_remap(bx, by);
    const int n0 = bx * 64, m0 = by * 128;

    const int lrow = tid >> 2;
    const int skq  = ((tid & 3) ^ ((tid >> 3) & 3)) * 8;
    const int lm   = lane & 15;
    const int qs   = (((lane >> 4) ^ ((lm >> 1) & 3)) * 8);

    const ushort* Bh_[3] = {Bqh, Bkh, Bvh};
    const ushort* Bl_[3] = {Bql, Bkl, Bvl};

    v4f aq[2][4], ak[2][4], av[2][4];
    const v4f vzero = {0.f, 0.f, 0.f, 0.f};
    #pragma unroll
    for (int i = 0; i < 2; ++i)
        #pragma unroll
        for (int j = 0; j < 4; ++j) { aq[i][j] = vzero; ak[i][j] = vzero; av[i][j] = vzero; }

    auto issue = [&](int kt, int st) {
        const long kk = (long)kt * 32 + skq;
        ushort* base = smem + st * STG;
        #pragma unroll
        for (int c = 0; c < 2; ++c) {
            const int row  = c * 64 + lrow;
            const int loff = (c * 64 + wv * 16) * 32;
            gload16(Ah + (long)(m0 + row) * 1024 + kk, base + loff);
            gload16(Al + (long)(m0 + row) * 1024 + kk, base + 4096 + loff);
        }
        const int loff = wv * 16 * 32;
        #pragma unroll
        for (int m = 0; m < 3; ++m) {
            gload16(Bh_[m] + (long)(n0 + lrow) * 1024 + kk, base + 8192 + m * 4096 + loff);
            gload16(Bl_[m] + (long)(n0 + lrow) * 1024 + kk, base + 8192 + m * 4096 + 2048 + loff);
        }
    };

    issue(0, 0);
    #pragma unroll 1
    for (int kt = 0; kt < 32; ++kt) {
        const int stg = kt & 1;
        if (kt) __builtin_amdgcn_s_barrier();
        const bool hasNext = (kt + 1 < 32);
        if (hasNext) issue(kt + 1, stg ^ 1);
        if (hasNext) wait_vm<10>(); else wait_vm<0>();
        __builtin_amdgcn_s_barrier();
        const ushort* As = smem + stg * STG;
        v8bf a[2], alo[2];
        #pragma unroll
        for (int i = 0; i < 2; ++i) {
            a[i]   = *(const v8bf*)(As + (wv*32 + 16*i + lm) * 32 + qs);
            alo[i] = *(const v8bf*)(As + 4096 + (wv*32 + 16*i + lm) * 32 + qs);
        }
        auto mat = [&](const ushort* Bs, v4f (&acc)[2][4]) {
            v8bf b[4], bl[4];
            #pragma unroll
            for (int j = 0; j < 4; ++j) {
                b[j]  = *(const v8bf*)(Bs + (16*j + lm) * 32 + qs);
                bl[j] = *(const v8bf*)(Bs + 2048 + (16*j + lm) * 32 + qs);
            }
            #pragma unroll
            for (int i = 0; i < 2; ++i)
                #pragma unroll
                for (int j = 0; j < 4; ++j) {
                    acc[i][j] = __builtin_amdgcn_mfma_f32_16x16x32_bf16(a[i],   b[j],  acc[i][j], 0, 0, 0);
                    acc[i][j] = __builtin_amdgcn_mfma_f32_16x16x32_bf16(a[i],   bl[j], acc[i][j], 0, 0, 0);
                    acc[i][j] = __builtin_amdgcn_mfma_f32_16x16x32_bf16(alo[i], b[j],  acc[i][j], 0, 0, 0);
                }
        };
        mat(As + 8192,        aq);
        mat(As + 8192 + 4096, ak);
        mat(As + 8192 + 8192, av);
    }

    const int r0 = (lane >> 4) * 4;
    #pragma unroll
    for (int i = 0; i < 2; ++i)
        #pragma unroll
        for (int j = 0; j < 4; ++j) {
            const int colg = n0 + 16*j + lm;
            #pragma unroll
            for (int r = 0; r < 4; ++r) {
                const long rowg = (long)(m0 + wv*32 + 16*i + r0 + r);
                const long idx  = rowg * 1024 + colg;
                Cq[idx] = aq[i][j][r];
                Ck[idx] = ak[i][j][r];
                ushort h, l; split_bf(av[i][j][r], h, l);
                Cvh[idx] = h;
                Cvl[idx] = l;
            }
        }
}

// ---------------------------------------------------------------------------
// MoE h1h3 fused GEMM v2: 128(M)x128(N) block, 512 threads = 8 waves (2x4),
// wave tile 64(M)x32(N), dual B (w1,w3). acc = 64 floats/wave; 8 ds_read_b128
// feed 16 MFMA and 128 MFMA per block-barrier. 3-stage LDS (72 KB), ONE
// barrier/K-step, 2-deep prefetch, wait_vm<3>. #pragma unroll 1 + manual
// stage counters keep the loop compact (no x3 unroll -> no spill).
// ---------------------------------------------------------------------------
__global__ __launch_bounds__(512, 2) void mgemm_h1h3(
    const ushort* __restrict__ Ah, const ushort* __restrict__ B1,
    const ushort* __restrict__ B2, ushort* __restrict__ Cb,
    const int* __restrict__ tokidx, const int* __restrict__ mbe,
    const int* __restrict__ mbm, long sB)
{
    constexpr int STG = 12288;  // A 4096 + B1 4096 + B2 4096 ushorts (24 KB)
    __shared__ __align__(16) ushort smem[3 * STG];

    const int tid  = threadIdx.x;
    const int wv   = tid >> 6, lane = tid & 63;
    const int wr   = wv >> 2, wc = wv & 3;    // 2 x 4 wave grid

    int bx = blockIdx.x, by = blockIdx.y;
    xcd_remap_cm(bx, by);
    const int n0 = bx * 128;
    const int eexp = mbe[by];
    if (eexp < 0) return;
    const int m0 = mbm[by];
    const long zB = (long)eexp * sB;

    const int lrow = tid >> 2;                              // 0..127
    const int skq  = ((tid & 3) ^ ((tid >> 3) & 3)) * 8;    // swizzled src slot
    const int lm   = lane & 15;
    const int qs   = (((lane >> 4) ^ ((lm >> 1) & 3)) * 8); // swizzled read slot

    const int t = tokidx[m0 + lrow];
    const long arow = (t < 0) ? 0 : (long)t;

    v4f acc[4][2], acc2[4][2];
    const v4f vzero = {0.f, 0.f, 0.f, 0.f};
    #pragma unroll
    for (int i = 0; i < 4; ++i)
        #pragma unroll
        for (int j = 0; j < 2; ++j) { acc[i][j] = vzero; acc2[i][j] = vzero; }

    auto issue = [&](int kt, int st) {
        const long kk = (long)kt * 32 + skq;
        ushort* base = smem + st * STG;
        const int loff = wv * 16 * 32;                       // 16 rows per wave
        gload16(Ah + arow * 1024 + kk, base + loff);
        gload16(B1 + zB + (long)(n0 + lrow) * 1024 + kk, base + 4096 + loff);
        gload16(B2 + zB + (long)(n0 + lrow) * 1024 + kk, base + 8192 + loff);
    };

    issue(0, 0);
    issue(1, 1);
    int s_cur = 0, s_nxt = 2;
    #pragma unroll 1
    for (int kt = 0; kt < 32; ++kt) {
        if (kt + 1 < 32) wait_vm<3>(); else wait_vm<0>();
        __builtin_amdgcn_s_barrier();
        if (kt + 2 < 32) issue(kt + 2, s_nxt);
        const ushort* As = smem + s_cur * STG;
        v8bf a[4], b1[2], b2[2];
        #pragma unroll
        for (int i = 0; i < 4; ++i) a[i] = *(const v8bf*)(As + (wr*64 + 16*i + lm) * 32 + qs);
        #pragma unroll
        for (int j = 0; j < 2; ++j) {
            b1[j] = *(const v8bf*)(As + 4096 + (wc*32 + 16*j + lm) * 32 + qs);
            b2[j] = *(const v8bf*)(As + 8192 + (wc*32 + 16*j + lm) * 32 + qs);
        }
        #pragma unroll
        for (int i = 0; i < 4; ++i)
            #pragma unroll
            for (int j = 0; j < 2; ++j) {
                acc[i][j]  = __builtin_amdgcn_mfma_f32_16x16x32_bf16(a[i], b1[j], acc[i][j],  0, 0, 0);
                acc2[i][j] = __builtin_amdgcn_mfma_f32_16x16x32_bf16(a[i], b2[j], acc2[i][j], 0, 0, 0);
            }
        s_cur = (s_cur == 2) ? 0 : s_cur + 1;
        s_nxt = (s_nxt == 2) ? 0 : s_nxt + 1;
    }

    const int r0 = (lane >> 4) * 4;
    #pragma unroll
    for (int i = 0; i < 4; ++i)
        #pragma unroll
        for (int j = 0; j < 2; ++j) {
            const int colg = n0 + wc*32 + 16*j + lm;
            #pragma unroll
            for (int r = 0; r < 4; ++r) {
                const long rowg = (long)(m0 + wr*64 + 16*i + r0 + r);
                Cb[rowg * HC + colg] = f2bf(sinf(acc[i][j][r]) * acc2[i][j][r]);
            }
        }
}

// ---------------------------------------------------------------------------
// Transpose fp32 [K][N] -> bf16 [N][K], optional hi/lo split.
// ---------------------------------------------------------------------------
template<bool SP>
__global__ __launch_bounds__(256) void transp(
    const float* __restrict__ in, ushort* __restrict__ oh, ushort* __restrict__ ol,
    int ldin, int ldout, long sIn, long sOut)
{
    __shared__ float T[64][65];
    const int n0 = blockIdx.x * 64, k0 = blockIdx.y * 64;
    in += (long)blockIdx.z * sIn;
    oh += (long)blockIdx.z * sOut;
    if (SP) ol += (long)blockIdx.z * sOut;
    const int t = threadIdx.x;
    const int rr = t >> 4, c4 = (t & 15) * 4;
    #pragma unroll
    for (int p = 0; p < 4; ++p) {
        const int r = rr + p * 16;
        const float4 v = *(const float4*)(in + (long)(k0 + r) * ldin + n0 + c4);
        T[c4+0][r] = v.x; T[c4+1][r] = v.y; T[c4+2][r] = v.z; T[c4+3][r] = v.w;
    }
    __syncthreads();
    #pragma unroll
    for (int p = 0; p < 4; ++p) {
        const int idx = t + 256 * p;
        const int n = idx >> 4, c = (idx & 15) * 4;
        ushort4 wh, wl;
        float x0 = T[n][c], x1 = T[n][c+1], x2 = T[n][c+2], x3 = T[n][c+3];
        if (SP) {
            split_bf(x0, wh.x, wl.x); split_bf(x1, wh.y, wl.y);
            split_bf(x2, wh.z, wl.z); split_bf(x3, wh.w, wl.w);
        } else {
            wh.x = f2bf(x0); wh.y = f2bf(x1); wh.z = f2bf(x2); wh.w = f2bf(x3);
        }
        *(ushort4*)(oh + (long)(n0 + n) * ldout + k0 + c) = wh;
        if (SP) *(ushort4*)(ol + (long)(n0 + n) * ldout + k0 + c) = wl;
    }
}

// ---------------------------------------------------------------------------
__global__ __launch_bounds__(256) void ada_kernel(
    const float* __restrict__ adaln, const float* __restrict__ aw,
    const float* __restrict__ ab, float* __restrict__ ada)
{
    __shared__ float s[DD];
    const int b = blockIdx.y;
    const int tid = threadIdx.x;
    for (int i = tid; i < DD; i += 256) {
        const float v = adaln[(long)b * DD + i];
        s[i] = v / (1.f + expf(-v));
    }
    __syncthreads();
    const int n = blockIdx.x * 256 + tid;
    float acc = 0.f;
    for (int k = 0; k < DD; ++k) acc += s[k] * aw[(long)k * SIXD + n];
    ada[(long)b * SIXD + n] = acc + ab[n];
}

// LayerNorm over D=1024; OUT: 0 fp32, 1 split bf16 hi/lo, 2 bf16
template<int OUT, bool MOD>
__global__ __launch_bounds__(256) void ln_kernel(
    const float* __restrict__ x, const float* __restrict__ w, const float* __restrict__ bias,
    const float* __restrict__ ada, int scale_off, int shift_off,
    float* __restrict__ o32, ushort* __restrict__ oh, ushort* __restrict__ ol, float eps)
{
    const int row = blockIdx.x;
    const int b = row >> 10;
    const int tid = threadIdx.x;
    const float* xr = x + (long)row * DD;
    float v[4]; float s = 0.f, q = 0.f;
    #pragma unroll
    for (int i = 0; i < 4; ++i) { v[i] = xr[tid + 256*i]; s += v[i]; q += v[i]*v[i]; }
    __shared__ float rs_[256], rq_[256];
    rs_[tid] = s; rq_[tid] = q; __syncthreads();
    for (int off = 128; off > 0; off >>= 1) {
        if (tid < off) { rs_[tid] += rs_[tid+off]; rq_[tid] += rq_[tid+off]; }
        __syncthreads();
    }
    const float mu  = rs_[0] * (1.f/DD);
    const float var = rq_[0] * (1.f/DD) - mu*mu;
    const float rstd = rsqrtf(var + eps);
    const float* ar = ada + (long)b * SIXD;
    #pragma unroll
    for (int i = 0; i < 4; ++i) {
        const int d = tid + 256*i;
        float y = (v[i] - mu) * rstd * w[d] + bias[d];
        if (MOD) y = y * (1.f + ar[scale_off + d]) + ar[shift_off + d];
        const long idx = (long)row * DD + d;
        if (OUT == 0) o32[idx] = y;
        else if (OUT == 1) { ushort h, l; split_bf(y, h, l); oh[idx] = h; ol[idx] = l; }
        else oh[idx] = f2bf(y);
    }
}

// Row softmax over 1024 -> split bf16 hi/lo
__global__ __launch_bounds__(256) void softmax_split(
    const float* __restrict__ in, ushort* __restrict__ oh, ushort* __restrict__ ol)
{
    const long row = blockIdx.x;
    const float* p = in + row * 1024;
    const int tid = threadIdx.x;
    float v[4]; float mx = -INFINITY;
    #pragma unroll
    for (int i = 0; i < 4; ++i) { v[i] = p[tid + 256*i]; mx = fmaxf(mx, v[i]); }
    __shared__ float red[256];
    red[tid] = mx; __syncthreads();
    for (int off = 128; off > 0; off >>= 1) {
        if (tid < off) red[tid] = fmaxf(red[tid], red[tid+off]);
        __syncthreads();
    }
    const float rowmax = red[0];
    __syncthreads();
    float s = 0.f;
    #pragma unroll
    for (int i = 0; i < 4; ++i) { v[i] = expf(v[i] - rowmax); s += v[i]; }
    red[tid] = s; __syncthreads();
    for (int off = 128; off > 0; off >>= 1) {
        if (tid < off) red[tid] += red[tid+off];
        __syncthreads();
    }
    const float inv = 1.f / red[0];
    #pragma unroll
    for (int i = 0; i < 4; ++i) {
        ushort h, l; split_bf(v[i] * inv, h, l);
        oh[row*1024 + tid + 256*i] = h;
        ol[row*1024 + tid + 256*i] = l;
    }
}

// Fused: h2 = modulate(ln(x2)) fp32, logits = h2 @ rw + rb (exact router)
__global__ __launch_bounds__(256) void router_fused(
    const float* __restrict__ x2, const float* __restrict__ fw, const float* __restrict__ fb,
    const float* __restrict__ ada, const float* __restrict__ rw, const float* __restrict__ rb,
    float* __restrict__ logits)
{
    const int row = blockIdx.x;
    const int b = row >> 10;
    const int tid = threadIdx.x;
    const float* xr = x2 + (long)row * DD;
    float v[4]; float s = 0.f, q = 0.f;
    #pragma unroll
    for (int i = 0; i < 4; ++i) { v[i] = xr[tid + 256*i]; s += v[i]; q += v[i]*v[i]; }
    __shared__ float rs_[256], rq_[256];
    rs_[tid] = s; rq_[tid] = q; __syncthreads();
    for (int off = 128; off > 0; off >>= 1) {
        if (tid < off) { rs_[tid] += rs_[tid+off]; rq_[tid] += rq_[tid+off]; }
        __syncthreads();
    }
    const float mu  = rs_[0] * (1.f/DD);
    const float var = rq_[0] * (1.f/DD) - mu*mu;
    const float rstd = rsqrtf(var + 1e-5f);
    const float* ar = ada + (long)b * SIXD;
    float acc[4] = {0.f, 0.f, 0.f, 0.f};
    #pragma unroll
    for (int i = 0; i < 4; ++i) {
        const int d = tid + 256*i;
        float h = (v[i] - mu) * rstd * fw[d] + fb[d];
        h = h * (1.f + ar[4096 + d]) + ar[3072 + d];
        const float* r4 = rw + (long)d * 4;
        acc[0] += h*r4[0]; acc[1] += h*r4[1]; acc[2] += h*r4[2]; acc[3] += h*r4[3];
    }
    __syncthreads();
    __shared__ float red[256];
    for (int e = 0; e < EE; ++e) {
        red[tid] = acc[e]; __syncthreads();
        for (int off = 128; off > 0; off >>= 1) {
            if (tid < off) red[tid] += red[tid+off];
            __syncthreads();
        }
        if (tid == 0) logits[(long)row * EE + e] = red[0] + rb[e];
        __syncthreads();
    }
}

// ---------------------------------------------------------------------------
// Merged router post-processing (single block, 1024 threads):
// seq-dim L2 norms, softmax, top-2 combine, aux loss, packed compaction
// with 128-aligned per-expert offsets and m-block map.
// Slot order within an expert is nondeterministic (atomics) — harmless.
// ---------------------------------------------------------------------------
__global__ __launch_bounds__(1024) void router_all(
    const float* __restrict__ logits, float* __restrict__ comb,
    float* __restrict__ auxout, int* __restrict__ tokidx,
    int* __restrict__ mbe, int* __restrict__ mbm)
{
    __shared__ float pl[16384];
    __shared__ float red[1024];
    __shared__ float nrm_l[16];
    __shared__ int lc[4], loff[4], lpos[4];
    const int tid = threadIdx.x;
    const int wv = tid >> 6, ln = tid & 63;
    // 1. L2 norms over seq dim: wave wv handles (b,e) = (wv>>2, wv&3)
    {
        const int b = wv >> 2, e = wv & 3;
        float s = 0.f;
        for (int it = 0; it < 16; ++it) {
            const float v = logits[(((long)b << 10) + ln + (it << 6)) * 4 + e];
            s += v * v;
        }
        for (int off = 32; off > 0; off >>= 1) s += __shfl_down(s, off, 64);
        if (ln == 0) nrm_l[wv] = fmaxf(sqrtf(s), 1e-12f);
    }
    if (tid < 4) lc[tid] = 0;
    __syncthreads();
    // 2. softmax + top-2 per row (4 rows/thread) + counts
    float cloc[4][4];
    const int rbase = tid * 4;
    for (int rr = 0; rr < 4; ++rr) {
        const int row = rbase + rr;
        const int b = row >> 10;
        float l[4], p[4];
        #pragma unroll
        for (int e = 0; e < 4; ++e) l[e] = logits[(long)row*4 + e] / nrm_l[b*4 + e];
        const float mx = fmaxf(fmaxf(l[0], l[1]), fmaxf(l[2], l[3]));
        float s = 0.f;
        #pragma unroll
        for (int e = 0; e < 4; ++e) { p[e] = expf(l[e] - mx); s += p[e]; }
        const float inv = 1.f / s;
        #pragma unroll
        for (int e = 0; e < 4; ++e) { p[e] *= inv; pl[row*4 + e] = p[e]; }
        int i1 = 0;
        #pragma unroll
        for (int e = 1; e < 4; ++e) if (p[e] > p[i1]) i1 = e;
        int i2 = (i1 == 0) ? 1 : 0;
        #pragma unroll
        for (int e = 0; e < 4; ++e) if (e != i1 && p[e] > p[i2]) i2 = e;
        #pragma unroll
        for (int e = 0; e < 4; ++e) {
            const float c = (e == i1) ? p[i1] : ((e == i2) ? p[i2] : 0.f);
            cloc[rr][e] = c;
            comb[(long)row*4 + e] = c;
            if (c > 0.f) atomicAdd(&lc[e], 1);
        }
    }
    __syncthreads();
    // 3. aux = sum_{s,e} (1/4 - mean_b p)^2
    float acc = 0.f;
    for (int i = tid; i < 4096; i += 1024) {
        const int s = i >> 2, e = i & 3;
        const float avg = 0.25f * (pl[s*4+e] + pl[(1024+s)*4+e] +
                                   pl[(2048+s)*4+e] + pl[(3072+s)*4+e]);
        const float d = 0.25f - avg;
        acc += d * d;
    }
    red[tid] = acc; __syncthreads();
    for (int off = 512; off > 0; off >>= 1) {
        if (tid < off) red[tid] += red[tid+off];
        __syncthreads();
    }
    if (tid == 0) auxout[0] = red[0];
    // 4. 128-aligned offsets + m-block map
    if (tid == 0) {
        int off0 = 0, nb = 0;
        for (int e = 0; e < 4; ++e) {
            loff[e] = off0; lpos[e] = 0;
            const int mb = (lc[e] + 127) >> 7;
            for (int k = 0; k < mb; ++k) { mbe[nb] = e; mbm[nb] = off0 + k*128; ++nb; }
            off0 += mb << 7;
        }
        for (; nb < NMB; ++nb) { mbe[nb] = -1; mbm[nb] = 0; }
    }
    for (int i = tid; i < NSLOT; i += 1024) tokidx[i] = -1;
    __syncthreads();
    // 5. fill slots
    for (int rr = 0; rr < 4; ++rr) {
        const int row = rbase + rr;
        #pragma unroll
        for (int e = 0; e < 4; ++e)
            if (cloc[rr][e] > 0.f) {
                const int s = atomicAdd(&lpos[e], 1);
                tokidx[loff[e] + s] = row;
            }
    }
}

__global__ __launch_bounds__(256) void zero_kernel(float4* __restrict__ out)
{
    out[(long)blockIdx.x * 256 + threadIdx.x] = float4{0.f, 0.f, 0.f, 0.f};
}

// ---------------------------------------------------------------------------
extern "C" void kernel_launch(void* const* d_in, const int* in_sizes, int n_in,
                              void* d_out, int out_size, void* d_ws, size_t ws_size,
                              hipStream_t stream)
{
    (void)in_sizes; (void)n_in; (void)out_size; (void)ws_size;
    const float* x     = (const float*)d_in[0];
    const float* adaln = (const float*)d_in[2];
    const float* wq    = (const float*)d_in[3];
    const float* wk    = (const float*)d_in[4];
    const float* wv    = (const float*)d_in[5];
    const float* wo    = (const float*)d_in[6];
    const float* qn_w  = (const float*)d_in[7];
    const float* qn_b  = (const float*)d_in[8];
    const float* kn_w  = (const float*)d_in[9];
    const float* kn_b  = (const float*)d_in[10];
    const float* an_w  = (const float*)d_in[11];
    const float* an_b  = (const float*)d_in[12];
    const float* fn_w  = (const float*)d_in[13];
    const float* fn_b  = (const float*)d_in[14];
    const float* w1    = (const float*)d_in[15];
    const float* w2    = (const float*)d_in[16];
    const float* w3    = (const float*)d_in[17];
    const float* rw    = (const float*)d_in[18];
    const float* rb    = (const float*)d_in[19];
    const float* aw    = (const float*)d_in[20];
    const float* ab    = (const float*)d_in[21];
    float* out = (float*)d_out;

    const long NBAT = (long)SS * DD;          // 1048576
    const long NBUF = (long)BB * SS * DD;     // 4194304
#define MB(x) ((long)(x) * 1048576L)

    char* P = (char*)d_ws;
    float* ada    = (float*)P;                       // 24576 f
    float* logits = (float*)(P + 98304);             // 16384 f
    float* comb   = logits + 16384;                  // 16384 f
    int*   tokidx = (int*)(comb + 16384);            // NSLOT
    int*   mbe    = tokidx + NSLOT;                  // NMB
    int*   mbm    = mbe + NMB;                       // NMB

    char* A0 = P + MB(1);
    // Region plan (16 MB units; each buffer annotated with live range):
    // [0,12):  wqT/wkT/wvT split (QKV inputs) -> woT [0,4) -> w1Tc [0,11.5)
    // [12,28): h split (QKV A) -> qT split -> ao split -> actb [12,36.5)
    // [28,44): q32 -> sc -> x2
    // [44,60): v split (persistent through step 10)
    // [60,76): k32 -> at split -> w3Tc [60,71.5)
    // [76,92): kT split -> h2bf [76,84); w2Tc [84,95.5)
    ushort* wqT_h = (ushort*)(A0 + MB(0));  ushort* wqT_l = (ushort*)(A0 + MB(2));
    ushort* wkT_h = (ushort*)(A0 + MB(4));  ushort* wkT_l = (ushort*)(A0 + MB(6));
    ushort* wvT_h = (ushort*)(A0 + MB(8));  ushort* wvT_l = (ushort*)(A0 + MB(10));
    ushort* woT_h = (ushort*)(A0 + MB(0));  ushort* woT_l = (ushort*)(A0 + MB(2));
    ushort* w1Tc  = (ushort*)(A0 + MB(0));           // [E][1408][1024] bf16
    ushort* h_h   = (ushort*)(A0 + MB(12)); ushort* h_l  = (ushort*)(A0 + MB(20));
    ushort* qT_h  = (ushort*)(A0 + MB(12)); ushort* qT_l = (ushort*)(A0 + MB(20));
    ushort* ao_h  = (ushort*)(A0 + MB(12)); ushort* ao_l = (ushort*)(A0 + MB(20));
    ushort* actb  = (ushort*)(A0 + MB(12));          // [8704][1408] bf16
    float*  q32   = (float*) (A0 + MB(28));
    float*  sc    = (float*) (A0 + MB(28));
    float*  x2    = (float*) (A0 + MB(28));
    ushort* v_h   = (ushort*)(A0 + MB(44)); ushort* v_l  = (ushort*)(A0 + MB(52));
    float*  k32   = (float*) (A0 + MB(60));
    ushort* at_h  = (ushort*)(A0 + MB(60)); ushort* at_l = (ushort*)(A0 + MB(68));
    ushort* w3Tc  = (ushort*)(A0 + MB(60));
    ushort* kT_h  = (ushort*)(A0 + MB(76)); ushort* kT_l = (ushort*)(A0 + MB(84));
    ushort* h2bf  = (ushort*)(A0 + MB(76));
    ushort* w2Tc  = (ushort*)(A0 + MB(84));          // [E][1024][1408] bf16

    const dim3 blk(256);

    // 1. adaLN vector
    ada_kernel<<<dim3(SIXD/256, BB), blk, 0, stream>>>(adaln, aw, ab, ada);

    // 2. attention weight transposes (split)
    transp<true><<<dim3(16,16,1), blk, 0, stream>>>(wq, wqT_h, wqT_l, 1024, 1024, 0, 0);
    transp<true><<<dim3(16,16,1), blk, 0, stream>>>(wk, wkT_h, wkT_l, 1024, 1024, 0, 0);
    transp<true><<<dim3(16,16,1), blk, 0, stream>>>(wv, wvT_h, wvT_l, 1024, 1024, 0, 0);

    // 3. h = modulate(ln(x)) -> split bf16
    ln_kernel<1,true><<<4096, blk, 0, stream>>>(x, an_w, an_b, ada, 1024, 0,
                                                nullptr, h_h, h_l, 1e-5f);

    // 4. fused QKV: q32, k32 fp32; v split bf16 (one pass over h)
    mgemm_qkv<<<dim3(16,32), blk, 0, stream>>>(
        h_h, h_l, wqT_h, wqT_l, wkT_h, wkT_l, wvT_h, wvT_l,
        q32, k32, v_h, v_l);

    // 5. q: LN, transpose-split (h region now dead -> qT)
    ln_kernel<0,false><<<4096, blk, 0, stream>>>(q32, qn_w, qn_b, ada, 0, 0, q32, nullptr, nullptr, 1e-5f);
    transp<true><<<dim3(16,16,BB), blk, 0, stream>>>(q32, qT_h, qT_l, 1024, 1024, NBAT, NBAT);

    // 6. k: LN, transpose-split
    ln_kernel<0,false><<<4096, blk, 0, stream>>>(k32, kn_w, kn_b, ada, 0, 0, k32, nullptr, nullptr, 1e-5f);
    transp<true><<<dim3(16,16,BB), blk, 0, stream>>>(k32, kT_h, kT_l, 1024, 1024, NBAT, NBAT);

    // 7. wo transpose (into reclaimed wqT region)
    transp<true><<<dim3(16,16,1), blk, 0, stream>>>(wo, woT_h, woT_l, 1024, 1024, 0, 0);

    // 8. scores[b,d,e] = sum_s qT[b,d,s]*kT[b,e,s] -> sc (q32 dead)
    mgemm<0,true,false><<<dim3(16,8,BB), blk, 0, stream>>>(
        qT_h, qT_l, kT_h, kT_l, sc, nullptr, nullptr, nullptr, nullptr, nullptr, nullptr,
        1024, 1024, 1024, 1024, NBAT, NBAT, NBAT);

    // 9. softmax -> attn split (k32 dead)
    softmax_split<<<4096, blk, 0, stream>>>(sc, at_h, at_l);

    // 10. ao[b,s,d] = sum_e v[b,s,e]*attn[b,d,e] -> split store (qT dead)
    mgemm<5,true,false><<<dim3(16,8,BB), blk, 0, stream>>>(
        v_h, v_l, at_h, at_l, ao_h, ao_l, nullptr, nullptr, nullptr, nullptr, nullptr,
        1024, 1024, 1024, 1024, NBAT, NBAT, NBAT);

    // 11. x2 = x + gate_msa * (ao @ wo)  (sc dead)
    mgemm<2,true,false><<<dim3(16,32,1), blk, 0, stream>>>(
        ao_h, ao_l, woT_h, woT_l, x2, nullptr, x, ada, nullptr, nullptr, nullptr,
        1024, 1024, 1024, 1024, 0, 0, 0);

    // 12. h2 = modulate(ln(x2)) -> bf16 (MoE input; kT region dead)
    ln_kernel<2,true><<<4096, blk, 0, stream>>>(x2, fn_w, fn_b, ada, 4096, 3072,
                                                nullptr, h2bf, nullptr, 1e-5f);

    // 13. router (exact fp32) + merged post/aux/compaction, zero out
    router_fused<<<4096, blk, 0, stream>>>(x2, fn_w, fn_b, ada, rw, rb, logits);
    router_all<<<1, dim3(1024), 0, stream>>>(logits, comb, out + NBUF, tokidx, mbe, mbm);
    zero_kernel<<<dim3(4096), blk, 0, stream>>>((float4*)out);

    // 14. MoE: top-2 sparse, HID chunked by 1408
    for (int c = 0; c < HID/HC; ++c) {
        transp<false><<<dim3(22,16,4), blk, 0, stream>>>(
            w1 + (long)c*HC, w1Tc, nullptr, HID, 1024, (long)DD*HID, (long)HC*1024);
        transp<false><<<dim3(22,16,4), blk, 0, stream>>>(
            w3 + (long)c*HC, w3Tc, nullptr, HID, 1024, (long)DD*HID, (long)HC*1024);
        transp<false><<<dim3(16,22,4), blk, 0, stream>>>(
            w2 + (long)c*HC*DD, w2Tc, nullptr, DD, HC, (long)HID*DD, (long)DD*HC);
        // act[slot] = bf16( sin(h2@w1c) * (h2@w3c) )  (gathered rows, dual-B, 128x128 / 8 waves)
        mgemm_h1h3<<<dim3(11, NMB), dim3(512), 0, stream>>>(
            h2bf, w1Tc, w3Tc, actb, tokidx, mbe, mbm, (long)HC*1024);
        // out[token] += comb[token,e] * (act @ w2c)  (atomic scatter)
        mgemm<7,false,true><<<dim3(16, NMB), blk, 0, stream>>>(
            actb, nullptr, w2Tc, nullptr, out, nullptr, comb, nullptr, tokidx, mbe, mbm,
            HC, HC, HC, 1024, 0, (long)DD*HC, 0);
    }
#undef MB
}